// Round 1
// baseline (3380.239 us; speedup 1.0000x reference)
//
#include <hip/hip_runtime.h>
#include <hip/hip_bf16.h>

#define NN 50000
#define EE 800000
constexpr float BN_EPS = 1e-5f;

// ---------------- degree / norm precompute ----------------
__global__ __launch_bounds__(256) void k_deg_init(float* deg) {
    int i = blockIdx.x * 256 + threadIdx.x;
    if (i < NN) deg[i] = 1.0f;
}
__global__ __launch_bounds__(256) void k_deg_acc(const int* __restrict__ dst,
                                                 const float* __restrict__ w,
                                                 float* deg) {
    int e = blockIdx.x * 256 + threadIdx.x;
    if (e < EE) unsafeAtomicAdd(&deg[dst[e]], w[e]);
}
__global__ __launch_bounds__(256) void k_dinv(float* deg) {
    int i = blockIdx.x * 256 + threadIdx.x;
    if (i < NN) deg[i] = rsqrtf(deg[i]);
}
__global__ __launch_bounds__(256) void k_norm(const int* __restrict__ src,
                                              const int* __restrict__ dst,
                                              const float* __restrict__ w,
                                              const float* __restrict__ dinv,
                                              float* __restrict__ nrm) {
    int e = blockIdx.x * 256 + threadIdx.x;
    if (e < EE) nrm[e] = dinv[src[e]] * w[e] * dinv[dst[e]];
}

// ---------------- fp32 tiled GEMM: Y[n x 128] = X[n x K] @ W[K x 128] ----------------
__global__ __launch_bounds__(256) void gemm128(const float* __restrict__ X,
                                               const float* __restrict__ W,
                                               float* __restrict__ Y,
                                               int n, int K) {
    __shared__ float xs[16][68];    // [kk][row], row stride 272B (16B-mult)
    __shared__ float ws[16][132];   // [kk][col], row stride 528B (16B-mult)
    int tid  = threadIdx.x;
    int row0 = blockIdx.x * 64;
    int tr = tid & 15;   // row group: rows tr*4 .. tr*4+3
    int tc = tid >> 4;   // col group: cols tc*8 .. tc*8+7
    float acc[4][8] = {};
    for (int k0 = 0; k0 < K; k0 += 16) {
        {   // stage X tile (transposed): 64 rows x 16 k
            int r  = tid >> 2;
            int kk = (tid & 3) * 4;
            int gr = row0 + r;
            float4 v = make_float4(0.f, 0.f, 0.f, 0.f);
            if (gr < n) v = *(const float4*)&X[(size_t)gr * K + k0 + kk];
            xs[kk + 0][r] = v.x; xs[kk + 1][r] = v.y;
            xs[kk + 2][r] = v.z; xs[kk + 3][r] = v.w;
        }
        {   // stage W tile: 16 k x 128 cols
            int kk = tid >> 4;
            int c  = (tid & 15) * 8;
            *(float4*)&ws[kk][c]     = *(const float4*)&W[(size_t)(k0 + kk) * 128 + c];
            *(float4*)&ws[kk][c + 4] = *(const float4*)&W[(size_t)(k0 + kk) * 128 + c + 4];
        }
        __syncthreads();
        #pragma unroll
        for (int kk = 0; kk < 16; kk++) {
            float a[4], b[8];
            *(float4*)a       = *(const float4*)&xs[kk][tr * 4];
            *(float4*)b       = *(const float4*)&ws[kk][tc * 8];
            *(float4*)(b + 4) = *(const float4*)&ws[kk][tc * 8 + 4];
            #pragma unroll
            for (int i = 0; i < 4; i++)
                #pragma unroll
                for (int j = 0; j < 8; j++)
                    acc[i][j] = fmaf(a[i], b[j], acc[i][j]);
        }
        __syncthreads();
    }
    #pragma unroll
    for (int i = 0; i < 4; i++) {
        int gr = row0 + tr * 4 + i;
        if (gr < n) {
            *(float4*)&Y[(size_t)gr * 128 + tc * 8]     = *(float4*)&acc[i][0];
            *(float4*)&Y[(size_t)gr * 128 + tc * 8 + 4] = *(float4*)&acc[i][4];
        }
    }
}

// ---------------- self-loop + bias init:  out = t * dinv_i^2 + b ----------------
__global__ __launch_bounds__(256) void k_self(const float* __restrict__ t,
                                              const float* __restrict__ dinv,
                                              const float* __restrict__ b,
                                              float* __restrict__ out) {
    int idx = blockIdx.x * 256 + threadIdx.x;     // one float4 each
    if (idx >= NN * 32) return;
    int i  = idx >> 5;
    int c4 = (idx & 31) * 4;
    float di = dinv[i];
    float s  = di * di;
    float4 v  = *(const float4*)&t[(size_t)i * 128 + c4];
    float4 bb = *(const float4*)&b[c4];
    float4 o  = make_float4(fmaf(v.x, s, bb.x), fmaf(v.y, s, bb.y),
                            fmaf(v.z, s, bb.z), fmaf(v.w, s, bb.w));
    *(float4*)&out[(size_t)i * 128 + c4] = o;
}

// ---------------- edge scatter:  out[dst] += t[src] * norm  (atomics) ----------------
__global__ __launch_bounds__(256) void k_scatter(const float* __restrict__ t,
                                                 const float* __restrict__ nrm,
                                                 const int* __restrict__ src,
                                                 const int* __restrict__ dst,
                                                 float* __restrict__ out) {
    int g    = blockIdx.x * 8 + (threadIdx.x >> 5);   // edge id (8 edges / block)
    int lane = threadIdx.x & 31;                      // 4 cols / lane
    if (g >= EE) return;
    int   s  = src[g];
    int   d  = dst[g];
    float nm = nrm[g];
    float4 v = *(const float4*)&t[(size_t)s * 128 + lane * 4];
    float* o = &out[(size_t)d * 128 + lane * 4];
    unsafeAtomicAdd(o + 0, v.x * nm);
    unsafeAtomicAdd(o + 1, v.y * nm);
    unsafeAtomicAdd(o + 2, v.z * nm);
    unsafeAtomicAdd(o + 3, v.w * nm);
}

// ---------------- in-place ReLU + per-block column partial sums ----------------
__global__ __launch_bounds__(256) void k_finish(float* __restrict__ h,
                                                float* __restrict__ partS,
                                                float* __restrict__ partSS) {
    int row0 = blockIdx.x * 64;
    int c    = threadIdx.x & 127;
    int half = threadIdx.x >> 7;   // 0 or 1
    float s = 0.f, ss = 0.f;
    for (int k = 0; k < 32; k++) {
        int r = row0 + half * 32 + k;
        if (r < NN) {
            float v = h[(size_t)r * 128 + c];
            v = fmaxf(v, 0.f);
            h[(size_t)r * 128 + c] = v;
            s += v; ss += v * v;
        }
    }
    __shared__ float ls[128], lss[128];
    if (half == 0) { ls[c] = s; lss[c] = ss; }
    __syncthreads();
    if (half == 1) { ls[c] += s; lss[c] += ss; }
    __syncthreads();
    if (half == 0) {
        partS [blockIdx.x * 128 + c] = ls[c];
        partSS[blockIdx.x * 128 + c] = lss[c];
    }
}

// ---------------- reduce partials -> BN scale/shift ----------------
__global__ void k_stats(const float* __restrict__ partS, const float* __restrict__ partSS,
                        int nblk, const float* __restrict__ g, const float* __restrict__ be,
                        float* __restrict__ scale, float* __restrict__ shift) {
    int c = threadIdx.x;   // 128 threads
    float s = 0.f, ss = 0.f;
    for (int b = 0; b < nblk; b++) { s += partS[b * 128 + c]; ss += partSS[b * 128 + c]; }
    float mean = s / (float)NN;
    float var  = ss / (float)NN - mean * mean;
    float sc   = g[c] * rsqrtf(var + BN_EPS);
    scale[c] = sc;
    shift[c] = be[c] - mean * sc;
}

// ---------------- in-place BN apply ----------------
__global__ __launch_bounds__(256) void k_bnapply(float* __restrict__ h,
                                                 const float* __restrict__ scale,
                                                 const float* __restrict__ shift) {
    int idx = blockIdx.x * 256 + threadIdx.x;
    if (idx >= NN * 32) return;
    int i  = idx >> 5;
    int c4 = (idx & 31) * 4;
    float4 v  = *(float4*)&h[(size_t)i * 128 + c4];
    float4 sc = *(const float4*)&scale[c4];
    float4 sh = *(const float4*)&shift[c4];
    v.x = fmaf(v.x, sc.x, sh.x); v.y = fmaf(v.y, sc.y, sh.y);
    v.z = fmaf(v.z, sc.z, sh.z); v.w = fmaf(v.w, sc.w, sh.w);
    *(float4*)&h[(size_t)i * 128 + c4] = v;
}

// ---------------- fused MLP head: K=384 GEMM + relu + 128->1 dot + relu ----------------
__global__ __launch_bounds__(256) void gemm_head(const float* __restrict__ X0,
                                                 const float* __restrict__ X1,
                                                 const float* __restrict__ X2,
                                                 const float* __restrict__ Wf1,
                                                 const float* __restrict__ bf1,
                                                 const float* __restrict__ Wf2,
                                                 const float* __restrict__ bf2,
                                                 float* __restrict__ out) {
    __shared__ float xs[16][68];
    __shared__ float ws[16][132];
    __shared__ float red[64];
    int tid  = threadIdx.x;
    int row0 = blockIdx.x * 64;
    int tr = tid & 15;
    int tc = tid >> 4;
    float acc[4][8] = {};
    for (int k0 = 0; k0 < 384; k0 += 16) {
        const float* S = (k0 < 128) ? X0 : (k0 < 256) ? X1 : X2;
        int kb = k0 & 127;
        {
            int r  = tid >> 2;
            int kk = (tid & 3) * 4;
            int gr = row0 + r;
            float4 v = make_float4(0.f, 0.f, 0.f, 0.f);
            if (gr < NN) v = *(const float4*)&S[(size_t)gr * 128 + kb + kk];
            xs[kk + 0][r] = v.x; xs[kk + 1][r] = v.y;
            xs[kk + 2][r] = v.z; xs[kk + 3][r] = v.w;
        }
        {
            int kk = tid >> 4;
            int c  = (tid & 15) * 8;
            *(float4*)&ws[kk][c]     = *(const float4*)&Wf1[(size_t)(k0 + kk) * 128 + c];
            *(float4*)&ws[kk][c + 4] = *(const float4*)&Wf1[(size_t)(k0 + kk) * 128 + c + 4];
        }
        __syncthreads();
        #pragma unroll
        for (int kk = 0; kk < 16; kk++) {
            float a[4], b[8];
            *(float4*)a       = *(const float4*)&xs[kk][tr * 4];
            *(float4*)b       = *(const float4*)&ws[kk][tc * 8];
            *(float4*)(b + 4) = *(const float4*)&ws[kk][tc * 8 + 4];
            #pragma unroll
            for (int i = 0; i < 4; i++)
                #pragma unroll
                for (int j = 0; j < 8; j++)
                    acc[i][j] = fmaf(a[i], b[j], acc[i][j]);
        }
        __syncthreads();
    }
    if (tid < 64) red[tid] = 0.f;
    __syncthreads();
    float w2[8];
    #pragma unroll
    for (int j = 0; j < 8; j++) w2[j] = Wf2[tc * 8 + j];
    #pragma unroll
    for (int i = 0; i < 4; i++) {
        float p = 0.f;
        #pragma unroll
        for (int j = 0; j < 8; j++) {
            float u = fmaxf(acc[i][j] + bf1[tc * 8 + j], 0.f);
            p = fmaf(u, w2[j], p);
        }
        atomicAdd(&red[tr * 4 + i], p);
    }
    __syncthreads();
    if (tid < 64 && row0 + tid < NN)
        out[row0 + tid] = fmaxf(red[tid] + bf2[0], 0.f);
}

// ---------------- launch ----------------
extern "C" void kernel_launch(void* const* d_in, const int* in_sizes, int n_in,
                              void* d_out, int out_size, void* d_ws, size_t ws_size,
                              hipStream_t stream) {
    const float* x   = (const float*)d_in[0];
    const int*   ei  = (const int*)d_in[1];
    const float* ew  = (const float*)d_in[2];
    const float* W1  = (const float*)d_in[3];
    const float* b1  = (const float*)d_in[4];
    const float* W2  = (const float*)d_in[5];
    const float* b2  = (const float*)d_in[6];
    const float* g1  = (const float*)d_in[7];
    const float* be1 = (const float*)d_in[8];
    const float* g2  = (const float*)d_in[9];
    const float* be2 = (const float*)d_in[10];
    const float* Wf1 = (const float*)d_in[11];
    const float* bf1 = (const float*)d_in[12];
    const float* Wf2 = (const float*)d_in[13];
    const float* bf2 = (const float*)d_in[14];
    float* out = (float*)d_out;

    const int* src = ei;
    const int* dst = ei + EE;

    // workspace carve (floats)
    float* w = (float*)d_ws;
    float* t      = w;               w += (size_t)NN * 128;   // 6.4M
    float* h1     = w;               w += (size_t)NN * 128;
    float* h2     = w;               w += (size_t)NN * 128;
    float* dinv   = w;               w += 50048;
    float* nrm    = w;               w += EE;
    const int NBLK = (NN + 63) / 64; // 782
    float* partS  = w;               w += (size_t)NBLK * 128;
    float* partSS = w;               w += (size_t)NBLK * 128;
    float* scale  = w;               w += 128;
    float* shift  = w;               w += 128;

    const int GN   = (NN + 255) / 256;
    const int GE   = (EE + 255) / 256;
    const int GEW  = EE / 8;             // scatter blocks (8 edges each)
    const int GELT = (NN * 32 + 255) / 256;

    // shared precompute
    k_deg_init<<<GN, 256, 0, stream>>>(dinv);
    k_deg_acc<<<GE, 256, 0, stream>>>(dst, ew, dinv);
    k_dinv<<<GN, 256, 0, stream>>>(dinv);
    k_norm<<<GE, 256, 0, stream>>>(src, dst, ew, dinv, nrm);

    // layer 1
    gemm128<<<NBLK, 256, 0, stream>>>(x, W1, t, NN, 128);
    k_self<<<GELT, 256, 0, stream>>>(t, dinv, b1, h1);
    k_scatter<<<GEW, 256, 0, stream>>>(t, nrm, src, dst, h1);
    k_finish<<<NBLK, 256, 0, stream>>>(h1, partS, partSS);
    k_stats<<<1, 128, 0, stream>>>(partS, partSS, NBLK, g1, be1, scale, shift);
    k_bnapply<<<GELT, 256, 0, stream>>>(h1, scale, shift);

    // layer 2
    gemm128<<<NBLK, 256, 0, stream>>>(h1, W2, t, NN, 128);
    k_self<<<GELT, 256, 0, stream>>>(t, dinv, b2, h2);
    k_scatter<<<GEW, 256, 0, stream>>>(t, nrm, src, dst, h2);
    k_finish<<<NBLK, 256, 0, stream>>>(h2, partS, partSS);
    k_stats<<<1, 128, 0, stream>>>(partS, partSS, NBLK, g2, be2, scale, shift);
    k_bnapply<<<GELT, 256, 0, stream>>>(h2, scale, shift);

    // head
    gemm_head<<<NBLK, 256, 0, stream>>>(x, h1, h2, Wf1, bf1, Wf2, bf2, out);
}

// Round 2
// 867.519 us; speedup vs baseline: 3.8964x; 3.8964x over previous
//
#include <hip/hip_runtime.h>
#include <hip/hip_bf16.h>

#define NN 50000
#define EE 800000
constexpr float BN_EPS = 1e-5f;

// ---------------- small utility kernels ----------------
__global__ __launch_bounds__(256) void k_zero_int(int* p, int n) {
    int i = blockIdx.x * 256 + threadIdx.x;
    if (i < n) p[i] = 0;
}
__global__ __launch_bounds__(256) void k_deg_init(float* deg) {
    int i = blockIdx.x * 256 + threadIdx.x;
    if (i < NN) deg[i] = 1.0f;
}
__global__ __launch_bounds__(256) void k_deg_acc(const int* __restrict__ dst,
                                                 const float* __restrict__ w,
                                                 float* deg) {
    int e = blockIdx.x * 256 + threadIdx.x;
    if (e < EE) unsafeAtomicAdd(&deg[dst[e]], w[e]);
}
__global__ __launch_bounds__(256) void k_dinv(float* deg) {
    int i = blockIdx.x * 256 + threadIdx.x;
    if (i < NN) deg[i] = rsqrtf(deg[i]);
}

// ---------------- CSR build: histogram -> scan -> place ----------------
__global__ __launch_bounds__(256) void k_hist(const int* __restrict__ dst, int* cnt) {
    int e = blockIdx.x * 256 + threadIdx.x;
    if (e < EE) atomicAdd(&cnt[dst[e]], 1);
}
// per-256-chunk exclusive scan + chunk sums
__global__ __launch_bounds__(256) void k_scan1(const int* __restrict__ cnt,
                                               int* __restrict__ excl,
                                               int* __restrict__ blksum) {
    __shared__ int sh[256];
    int tid = threadIdx.x;
    int i = blockIdx.x * 256 + tid;
    int v = (i < NN) ? cnt[i] : 0;
    sh[tid] = v;
    __syncthreads();
    #pragma unroll
    for (int off = 1; off < 256; off <<= 1) {
        int x = (tid >= off) ? sh[tid - off] : 0;
        __syncthreads();
        sh[tid] += x;
        __syncthreads();
    }
    if (i < NN) excl[i] = sh[tid] - v;
    if (tid == 255) blksum[blockIdx.x] = sh[255];
}
// single-block inclusive scan of chunk sums (nblk <= 256)
__global__ __launch_bounds__(256) void k_scan2(int* blksum, int nblk) {
    __shared__ int sh[256];
    int tid = threadIdx.x;
    sh[tid] = (tid < nblk) ? blksum[tid] : 0;
    __syncthreads();
    #pragma unroll
    for (int off = 1; off < 256; off <<= 1) {
        int x = (tid >= off) ? sh[tid - off] : 0;
        __syncthreads();
        sh[tid] += x;
        __syncthreads();
    }
    if (tid < nblk) blksum[tid] = sh[tid];
}
// rowptr = chunk-exclusive + prior-chunk total; rowptr[NN] = EE
__global__ __launch_bounds__(256) void k_scan3(const int* __restrict__ excl,
                                               const int* __restrict__ blksum,
                                               int* __restrict__ rowptr) {
    int i = blockIdx.x * 256 + threadIdx.x;
    if (i < NN)
        rowptr[i] = excl[i] + (blockIdx.x > 0 ? blksum[blockIdx.x - 1] : 0);
    if (i == 0) rowptr[NN] = EE;
}
// place edges into CSR slots; compute nrm inline
__global__ __launch_bounds__(256) void k_place(const int* __restrict__ src,
                                               const int* __restrict__ dst,
                                               const float* __restrict__ w,
                                               const float* __restrict__ dinv,
                                               const int* __restrict__ rowptr,
                                               int* __restrict__ fill,
                                               int* __restrict__ csr_src,
                                               float* __restrict__ csr_nrm) {
    int e = blockIdx.x * 256 + threadIdx.x;
    if (e >= EE) return;
    int s = src[e];
    int d = dst[e];
    int slot = rowptr[d] + atomicAdd(&fill[d], 1);
    csr_src[slot] = s;
    csr_nrm[slot] = dinv[s] * w[e] * dinv[d];
}

// ---------------- fp32 tiled GEMM: Y[n x 128] = X[n x K] @ W[K x 128] ----------------
__global__ __launch_bounds__(256) void gemm128(const float* __restrict__ X,
                                               const float* __restrict__ W,
                                               float* __restrict__ Y,
                                               int n, int K) {
    __shared__ float xs[16][68];
    __shared__ float ws[16][132];
    int tid  = threadIdx.x;
    int row0 = blockIdx.x * 64;
    int tr = tid & 15;
    int tc = tid >> 4;
    float acc[4][8] = {};
    for (int k0 = 0; k0 < K; k0 += 16) {
        {
            int r  = tid >> 2;
            int kk = (tid & 3) * 4;
            int gr = row0 + r;
            float4 v = make_float4(0.f, 0.f, 0.f, 0.f);
            if (gr < n) v = *(const float4*)&X[(size_t)gr * K + k0 + kk];
            xs[kk + 0][r] = v.x; xs[kk + 1][r] = v.y;
            xs[kk + 2][r] = v.z; xs[kk + 3][r] = v.w;
        }
        {
            int kk = tid >> 4;
            int c  = (tid & 15) * 8;
            *(float4*)&ws[kk][c]     = *(const float4*)&W[(size_t)(k0 + kk) * 128 + c];
            *(float4*)&ws[kk][c + 4] = *(const float4*)&W[(size_t)(k0 + kk) * 128 + c + 4];
        }
        __syncthreads();
        #pragma unroll
        for (int kk = 0; kk < 16; kk++) {
            float a[4], b[8];
            *(float4*)a       = *(const float4*)&xs[kk][tr * 4];
            *(float4*)b       = *(const float4*)&ws[kk][tc * 8];
            *(float4*)(b + 4) = *(const float4*)&ws[kk][tc * 8 + 4];
            #pragma unroll
            for (int i = 0; i < 4; i++)
                #pragma unroll
                for (int j = 0; j < 8; j++)
                    acc[i][j] = fmaf(a[i], b[j], acc[i][j]);
        }
        __syncthreads();
    }
    #pragma unroll
    for (int i = 0; i < 4; i++) {
        int gr = row0 + tr * 4 + i;
        if (gr < n) {
            *(float4*)&Y[(size_t)gr * 128 + tc * 8]     = *(float4*)&acc[i][0];
            *(float4*)&Y[(size_t)gr * 128 + tc * 8 + 4] = *(float4*)&acc[i][4];
        }
    }
}

// ---------------- aggregate (pull): one wave per dst node ----------------
// out[i] = t[i]*dinv_i^2 + b + sum_e t[csr_src[e]] * csr_nrm[e]
__global__ __launch_bounds__(256) void k_aggregate(const float* __restrict__ t,
                                                   const float* __restrict__ dinv,
                                                   const float* __restrict__ b,
                                                   const int* __restrict__ rowptr,
                                                   const int* __restrict__ csr_src,
                                                   const float* __restrict__ csr_nrm,
                                                   float* __restrict__ out) {
    int wid  = (blockIdx.x * 256 + threadIdx.x) >> 6;   // node id
    int lane = threadIdx.x & 63;                        // 2 cols per lane
    if (wid >= NN) return;
    float di = dinv[wid];
    float s2 = di * di;
    float2 acc = *(const float2*)&t[(size_t)wid * 128 + lane * 2];
    float2 bb  = *(const float2*)&b[lane * 2];
    acc.x = fmaf(acc.x, s2, bb.x);
    acc.y = fmaf(acc.y, s2, bb.y);
    int e  = rowptr[wid];
    int e1 = rowptr[wid + 1];
    for (; e + 1 < e1; e += 2) {
        int   s0 = csr_src[e],     s1 = csr_src[e + 1];
        float n0 = csr_nrm[e],     n1 = csr_nrm[e + 1];
        float2 v0 = *(const float2*)&t[(size_t)s0 * 128 + lane * 2];
        float2 v1 = *(const float2*)&t[(size_t)s1 * 128 + lane * 2];
        acc.x = fmaf(v0.x, n0, acc.x); acc.y = fmaf(v0.y, n0, acc.y);
        acc.x = fmaf(v1.x, n1, acc.x); acc.y = fmaf(v1.y, n1, acc.y);
    }
    if (e < e1) {
        int   s0 = csr_src[e];
        float n0 = csr_nrm[e];
        float2 v0 = *(const float2*)&t[(size_t)s0 * 128 + lane * 2];
        acc.x = fmaf(v0.x, n0, acc.x); acc.y = fmaf(v0.y, n0, acc.y);
    }
    *(float2*)&out[(size_t)wid * 128 + lane * 2] = acc;
}

// ---------------- in-place ReLU + per-block column partial sums ----------------
__global__ __launch_bounds__(256) void k_finish(float* __restrict__ h,
                                                float* __restrict__ partS,
                                                float* __restrict__ partSS) {
    int row0 = blockIdx.x * 64;
    int c    = threadIdx.x & 127;
    int half = threadIdx.x >> 7;
    float s = 0.f, ss = 0.f;
    for (int k = 0; k < 32; k++) {
        int r = row0 + half * 32 + k;
        if (r < NN) {
            float v = h[(size_t)r * 128 + c];
            v = fmaxf(v, 0.f);
            h[(size_t)r * 128 + c] = v;
            s += v; ss += v * v;
        }
    }
    __shared__ float ls[128], lss[128];
    if (half == 0) { ls[c] = s; lss[c] = ss; }
    __syncthreads();
    if (half == 1) { ls[c] += s; lss[c] += ss; }
    __syncthreads();
    if (half == 0) {
        partS [blockIdx.x * 128 + c] = ls[c];
        partSS[blockIdx.x * 128 + c] = lss[c];
    }
}

// ---------------- reduce partials -> BN scale/shift ----------------
__global__ void k_stats(const float* __restrict__ partS, const float* __restrict__ partSS,
                        int nblk, const float* __restrict__ g, const float* __restrict__ be,
                        float* __restrict__ scale, float* __restrict__ shift) {
    int c = threadIdx.x;
    float s = 0.f, ss = 0.f;
    for (int b = 0; b < nblk; b++) { s += partS[b * 128 + c]; ss += partSS[b * 128 + c]; }
    float mean = s / (float)NN;
    float var  = ss / (float)NN - mean * mean;
    float sc   = g[c] * rsqrtf(var + BN_EPS);
    scale[c] = sc;
    shift[c] = be[c] - mean * sc;
}

// ---------------- in-place BN apply ----------------
__global__ __launch_bounds__(256) void k_bnapply(float* __restrict__ h,
                                                 const float* __restrict__ scale,
                                                 const float* __restrict__ shift) {
    int idx = blockIdx.x * 256 + threadIdx.x;
    if (idx >= NN * 32) return;
    int i  = idx >> 5;
    int c4 = (idx & 31) * 4;
    float4 v  = *(float4*)&h[(size_t)i * 128 + c4];
    float4 sc = *(const float4*)&scale[c4];
    float4 sh = *(const float4*)&shift[c4];
    v.x = fmaf(v.x, sc.x, sh.x); v.y = fmaf(v.y, sc.y, sh.y);
    v.z = fmaf(v.z, sc.z, sh.z); v.w = fmaf(v.w, sc.w, sh.w);
    *(float4*)&h[(size_t)i * 128 + c4] = v;
}

// ---------------- fused MLP head: K=384 GEMM + relu + 128->1 dot + relu ----------------
__global__ __launch_bounds__(256) void gemm_head(const float* __restrict__ X0,
                                                 const float* __restrict__ X1,
                                                 const float* __restrict__ X2,
                                                 const float* __restrict__ Wf1,
                                                 const float* __restrict__ bf1,
                                                 const float* __restrict__ Wf2,
                                                 const float* __restrict__ bf2,
                                                 float* __restrict__ out) {
    __shared__ float xs[16][68];
    __shared__ float ws[16][132];
    __shared__ float red[64];
    int tid  = threadIdx.x;
    int row0 = blockIdx.x * 64;
    int tr = tid & 15;
    int tc = tid >> 4;
    float acc[4][8] = {};
    for (int k0 = 0; k0 < 384; k0 += 16) {
        const float* S = (k0 < 128) ? X0 : (k0 < 256) ? X1 : X2;
        int kb = k0 & 127;
        {
            int r  = tid >> 2;
            int kk = (tid & 3) * 4;
            int gr = row0 + r;
            float4 v = make_float4(0.f, 0.f, 0.f, 0.f);
            if (gr < NN) v = *(const float4*)&S[(size_t)gr * 128 + kb + kk];
            xs[kk + 0][r] = v.x; xs[kk + 1][r] = v.y;
            xs[kk + 2][r] = v.z; xs[kk + 3][r] = v.w;
        }
        {
            int kk = tid >> 4;
            int c  = (tid & 15) * 8;
            *(float4*)&ws[kk][c]     = *(const float4*)&Wf1[(size_t)(k0 + kk) * 128 + c];
            *(float4*)&ws[kk][c + 4] = *(const float4*)&Wf1[(size_t)(k0 + kk) * 128 + c + 4];
        }
        __syncthreads();
        #pragma unroll
        for (int kk = 0; kk < 16; kk++) {
            float a[4], b[8];
            *(float4*)a       = *(const float4*)&xs[kk][tr * 4];
            *(float4*)b       = *(const float4*)&ws[kk][tc * 8];
            *(float4*)(b + 4) = *(const float4*)&ws[kk][tc * 8 + 4];
            #pragma unroll
            for (int i = 0; i < 4; i++)
                #pragma unroll
                for (int j = 0; j < 8; j++)
                    acc[i][j] = fmaf(a[i], b[j], acc[i][j]);
        }
        __syncthreads();
    }
    if (tid < 64) red[tid] = 0.f;
    __syncthreads();
    float w2[8];
    #pragma unroll
    for (int j = 0; j < 8; j++) w2[j] = Wf2[tc * 8 + j];
    #pragma unroll
    for (int i = 0; i < 4; i++) {
        float p = 0.f;
        #pragma unroll
        for (int j = 0; j < 8; j++) {
            float u = fmaxf(acc[i][j] + bf1[tc * 8 + j], 0.f);
            p = fmaf(u, w2[j], p);
        }
        atomicAdd(&red[tr * 4 + i], p);
    }
    __syncthreads();
    if (tid < 64 && row0 + tid < NN)
        out[row0 + tid] = fmaxf(red[tid] + bf2[0], 0.f);
}

// ---------------- launch ----------------
extern "C" void kernel_launch(void* const* d_in, const int* in_sizes, int n_in,
                              void* d_out, int out_size, void* d_ws, size_t ws_size,
                              hipStream_t stream) {
    const float* x   = (const float*)d_in[0];
    const int*   ei  = (const int*)d_in[1];
    const float* ew  = (const float*)d_in[2];
    const float* W1  = (const float*)d_in[3];
    const float* b1  = (const float*)d_in[4];
    const float* W2  = (const float*)d_in[5];
    const float* b2  = (const float*)d_in[6];
    const float* g1  = (const float*)d_in[7];
    const float* be1 = (const float*)d_in[8];
    const float* g2  = (const float*)d_in[9];
    const float* be2 = (const float*)d_in[10];
    const float* Wf1 = (const float*)d_in[11];
    const float* bf1 = (const float*)d_in[12];
    const float* Wf2 = (const float*)d_in[13];
    const float* bf2 = (const float*)d_in[14];
    float* out = (float*)d_out;

    const int* src = ei;
    const int* dst = ei + EE;

    // workspace carve
    float* w = (float*)d_ws;
    float* t       = w;  w += (size_t)NN * 128;
    float* h1      = w;  w += (size_t)NN * 128;
    float* h2      = w;  w += (size_t)NN * 128;
    float* dinv    = w;  w += 50048;
    const int NBLK = (NN + 63) / 64;  // 782
    float* partS   = w;  w += (size_t)NBLK * 128;
    float* partSS  = w;  w += (size_t)NBLK * 128;
    float* scale   = w;  w += 128;
    float* shift   = w;  w += 128;
    float* csr_nrm = w;  w += EE;
    int* iw        = (int*)w;
    int* rowptr    = iw; iw += 50056;
    int* cnt       = iw; iw += 50048;
    int* excl      = iw; iw += 50048;
    int* fill      = iw; iw += 50048;
    int* blksum    = iw; iw += 256;
    int* csr_src   = iw; iw += EE;

    const int GN      = (NN + 255) / 256;       // 196
    const int GE      = (EE + 255) / 256;
    const int GELT    = (NN * 32 + 255) / 256;
    const int GAGG    = (NN * 64 + 255) / 256;  // 1 wave per node, 4 waves/block

    // degree / dinv
    k_deg_init<<<GN, 256, 0, stream>>>(dinv);
    k_deg_acc<<<GE, 256, 0, stream>>>(dst, ew, dinv);
    k_dinv<<<GN, 256, 0, stream>>>(dinv);

    // CSR build (shared by both layers)
    k_zero_int<<<GN, 256, 0, stream>>>(cnt, NN);
    k_zero_int<<<GN, 256, 0, stream>>>(fill, NN);
    k_hist<<<GE, 256, 0, stream>>>(dst, cnt);
    k_scan1<<<GN, 256, 0, stream>>>(cnt, excl, blksum);
    k_scan2<<<1, 256, 0, stream>>>(blksum, GN);
    k_scan3<<<GN, 256, 0, stream>>>(excl, blksum, rowptr);
    k_place<<<GE, 256, 0, stream>>>(src, dst, ew, dinv, rowptr, fill, csr_src, csr_nrm);

    // layer 1
    gemm128<<<NBLK, 256, 0, stream>>>(x, W1, t, NN, 128);
    k_aggregate<<<GAGG, 256, 0, stream>>>(t, dinv, b1, rowptr, csr_src, csr_nrm, h1);
    k_finish<<<NBLK, 256, 0, stream>>>(h1, partS, partSS);
    k_stats<<<1, 128, 0, stream>>>(partS, partSS, NBLK, g1, be1, scale, shift);
    k_bnapply<<<GELT, 256, 0, stream>>>(h1, scale, shift);

    // layer 2
    gemm128<<<NBLK, 256, 0, stream>>>(h1, W2, t, NN, 128);
    k_aggregate<<<GAGG, 256, 0, stream>>>(t, dinv, b2, rowptr, csr_src, csr_nrm, h2);
    k_finish<<<NBLK, 256, 0, stream>>>(h2, partS, partSS);
    k_stats<<<1, 128, 0, stream>>>(partS, partSS, NBLK, g2, be2, scale, shift);
    k_bnapply<<<GELT, 256, 0, stream>>>(h2, scale, shift);

    // head
    gemm_head<<<NBLK, 256, 0, stream>>>(x, h1, h2, Wf1, bf1, Wf2, bf2, out);
}

// Round 3
// 451.337 us; speedup vs baseline: 7.4894x; 1.9221x over previous
//
#include <hip/hip_runtime.h>
#include <hip/hip_bf16.h>

#define NN 50000
#define EE 800000
constexpr float BN_EPS = 1e-5f;

// ---------------- small utility kernels ----------------
__global__ __launch_bounds__(256) void k_zero_int(int* p, int n) {
    int i = blockIdx.x * 256 + threadIdx.x;
    if (i < n) p[i] = 0;
}
__global__ __launch_bounds__(256) void k_deg_init(float* deg) {
    int i = blockIdx.x * 256 + threadIdx.x;
    if (i < NN) deg[i] = 1.0f;
}
// degree accumulate + dst histogram in one edge pass
__global__ __launch_bounds__(256) void k_deg_hist(const int* __restrict__ dst,
                                                  const float* __restrict__ w,
                                                  float* deg, int* cnt) {
    int e = blockIdx.x * 256 + threadIdx.x;
    if (e < EE) {
        int d = dst[e];
        unsafeAtomicAdd(&deg[d], w[e]);
        atomicAdd(&cnt[d], 1);
    }
}
__global__ __launch_bounds__(256) void k_dinv(float* deg) {
    int i = blockIdx.x * 256 + threadIdx.x;
    if (i < NN) deg[i] = rsqrtf(deg[i]);
}

// ---------------- CSR build: scan -> place ----------------
__global__ __launch_bounds__(256) void k_scan1(const int* __restrict__ cnt,
                                               int* __restrict__ excl,
                                               int* __restrict__ blksum) {
    __shared__ int sh[256];
    int tid = threadIdx.x;
    int i = blockIdx.x * 256 + tid;
    int v = (i < NN) ? cnt[i] : 0;
    sh[tid] = v;
    __syncthreads();
    #pragma unroll
    for (int off = 1; off < 256; off <<= 1) {
        int x = (tid >= off) ? sh[tid - off] : 0;
        __syncthreads();
        sh[tid] += x;
        __syncthreads();
    }
    if (i < NN) excl[i] = sh[tid] - v;
    if (tid == 255) blksum[blockIdx.x] = sh[255];
}
__global__ __launch_bounds__(256) void k_scan2(int* blksum, int nblk) {
    __shared__ int sh[256];
    int tid = threadIdx.x;
    sh[tid] = (tid < nblk) ? blksum[tid] : 0;
    __syncthreads();
    #pragma unroll
    for (int off = 1; off < 256; off <<= 1) {
        int x = (tid >= off) ? sh[tid - off] : 0;
        __syncthreads();
        sh[tid] += x;
        __syncthreads();
    }
    if (tid < nblk) blksum[tid] = sh[tid];
}
__global__ __launch_bounds__(256) void k_scan3(const int* __restrict__ excl,
                                               const int* __restrict__ blksum,
                                               int* __restrict__ rowptr) {
    int i = blockIdx.x * 256 + threadIdx.x;
    if (i < NN)
        rowptr[i] = excl[i] + (blockIdx.x > 0 ? blksum[blockIdx.x - 1] : 0);
    if (i == 0) rowptr[NN] = EE;
}
__global__ __launch_bounds__(256) void k_place(const int* __restrict__ src,
                                               const int* __restrict__ dst,
                                               const float* __restrict__ w,
                                               const float* __restrict__ dinv,
                                               const int* __restrict__ rowptr,
                                               int* __restrict__ fill,
                                               int* __restrict__ csr_src,
                                               float* __restrict__ csr_nrm) {
    int e = blockIdx.x * 256 + threadIdx.x;
    if (e >= EE) return;
    int s = src[e];
    int d = dst[e];
    int slot = rowptr[d] + atomicAdd(&fill[d], 1);
    csr_src[slot] = s;
    csr_nrm[slot] = dinv[s] * w[e] * dinv[d];
}

// ---------------- fp32 tiled GEMM: Y[n x 128] = X[n x K] @ W[K x 128] ----------------
__global__ __launch_bounds__(256) void gemm128(const float* __restrict__ X,
                                               const float* __restrict__ W,
                                               float* __restrict__ Y,
                                               int n, int K) {
    __shared__ float xs[16][68];
    __shared__ float ws[16][132];
    int tid  = threadIdx.x;
    int row0 = blockIdx.x * 64;
    int tr = tid & 15;
    int tc = tid >> 4;
    float acc[4][8] = {};
    for (int k0 = 0; k0 < K; k0 += 16) {
        {
            int r  = tid >> 2;
            int kk = (tid & 3) * 4;
            int gr = row0 + r;
            float4 v = make_float4(0.f, 0.f, 0.f, 0.f);
            if (gr < n) v = *(const float4*)&X[(size_t)gr * K + k0 + kk];
            xs[kk + 0][r] = v.x; xs[kk + 1][r] = v.y;
            xs[kk + 2][r] = v.z; xs[kk + 3][r] = v.w;
        }
        {
            int kk = tid >> 4;
            int c  = (tid & 15) * 8;
            *(float4*)&ws[kk][c]     = *(const float4*)&W[(size_t)(k0 + kk) * 128 + c];
            *(float4*)&ws[kk][c + 4] = *(const float4*)&W[(size_t)(k0 + kk) * 128 + c + 4];
        }
        __syncthreads();
        #pragma unroll
        for (int kk = 0; kk < 16; kk++) {
            float a[4], b[8];
            *(float4*)a       = *(const float4*)&xs[kk][tr * 4];
            *(float4*)b       = *(const float4*)&ws[kk][tc * 8];
            *(float4*)(b + 4) = *(const float4*)&ws[kk][tc * 8 + 4];
            #pragma unroll
            for (int i = 0; i < 4; i++)
                #pragma unroll
                for (int j = 0; j < 8; j++)
                    acc[i][j] = fmaf(a[i], b[j], acc[i][j]);
        }
        __syncthreads();
    }
    #pragma unroll
    for (int i = 0; i < 4; i++) {
        int gr = row0 + tr * 4 + i;
        if (gr < n) {
            *(float4*)&Y[(size_t)gr * 128 + tc * 8]     = *(float4*)&acc[i][0];
            *(float4*)&Y[(size_t)gr * 128 + tc * 8 + 4] = *(float4*)&acc[i][4];
        }
    }
}

// ---------------- aggregate (pull) + ReLU: one wave per dst node ----------------
// out[i] = relu( t[i]*dinv_i^2 + b + sum_e t[csr_src[e]] * csr_nrm[e] )
__global__ __launch_bounds__(256) void k_aggregate(const float* __restrict__ t,
                                                   const float* __restrict__ dinv,
                                                   const float* __restrict__ b,
                                                   const int* __restrict__ rowptr,
                                                   const int* __restrict__ csr_src,
                                                   const float* __restrict__ csr_nrm,
                                                   float* __restrict__ out) {
    int wid  = (blockIdx.x * 256 + threadIdx.x) >> 6;   // node id
    int lane = threadIdx.x & 63;                        // 2 cols per lane
    if (wid >= NN) return;
    float di = dinv[wid];
    float s2 = di * di;
    float2 acc = *(const float2*)&t[(size_t)wid * 128 + lane * 2];
    float2 bb  = *(const float2*)&b[lane * 2];
    acc.x = fmaf(acc.x, s2, bb.x);
    acc.y = fmaf(acc.y, s2, bb.y);
    int e  = rowptr[wid];
    int e1 = rowptr[wid + 1];
    for (; e + 1 < e1; e += 2) {
        int   s0 = csr_src[e],     s1 = csr_src[e + 1];
        float n0 = csr_nrm[e],     n1 = csr_nrm[e + 1];
        float2 v0 = *(const float2*)&t[(size_t)s0 * 128 + lane * 2];
        float2 v1 = *(const float2*)&t[(size_t)s1 * 128 + lane * 2];
        acc.x = fmaf(v0.x, n0, acc.x); acc.y = fmaf(v0.y, n0, acc.y);
        acc.x = fmaf(v1.x, n1, acc.x); acc.y = fmaf(v1.y, n1, acc.y);
    }
    if (e < e1) {
        int   s0 = csr_src[e];
        float n0 = csr_nrm[e];
        float2 v0 = *(const float2*)&t[(size_t)s0 * 128 + lane * 2];
        acc.x = fmaf(v0.x, n0, acc.x); acc.y = fmaf(v0.y, n0, acc.y);
    }
    acc.x = fmaxf(acc.x, 0.f);
    acc.y = fmaxf(acc.y, 0.f);
    *(float2*)&out[(size_t)wid * 128 + lane * 2] = acc;
}

// ---------------- per-block column partial sums (read-only; h already relu'd) ----------------
__global__ __launch_bounds__(256) void k_colsum(const float* __restrict__ h,
                                                float* __restrict__ partS,
                                                float* __restrict__ partSS) {
    int row0 = blockIdx.x * 64;
    int c    = threadIdx.x & 127;
    int half = threadIdx.x >> 7;
    float s = 0.f, ss = 0.f;
    for (int k = 0; k < 32; k++) {
        int r = row0 + half * 32 + k;
        if (r < NN) {
            float v = h[(size_t)r * 128 + c];
            s += v; ss += v * v;
        }
    }
    __shared__ float ls[128], lss[128];
    if (half == 0) { ls[c] = s; lss[c] = ss; }
    __syncthreads();
    if (half == 1) { ls[c] += s; lss[c] += ss; }
    __syncthreads();
    if (half == 0) {
        partS [blockIdx.x * 128 + c] = ls[c];
        partSS[blockIdx.x * 128 + c] = lss[c];
    }
}

// ---------------- parallel reduce partials -> BN scale/shift (1 block per column) ----------------
__global__ __launch_bounds__(256) void k_stats(const float* __restrict__ partS,
                                               const float* __restrict__ partSS,
                                               int nblk,
                                               const float* __restrict__ g,
                                               const float* __restrict__ be,
                                               float* __restrict__ scale,
                                               float* __restrict__ shift) {
    int c   = blockIdx.x;     // column 0..127
    int tid = threadIdx.x;
    float s = 0.f, ss = 0.f;
    for (int b = tid; b < nblk; b += 256) {
        s  += partS [b * 128 + c];
        ss += partSS[b * 128 + c];
    }
    #pragma unroll
    for (int off = 32; off > 0; off >>= 1) {
        s  += __shfl_down(s,  off, 64);
        ss += __shfl_down(ss, off, 64);
    }
    __shared__ float sh_s[4], sh_ss[4];
    int w = tid >> 6, lane = tid & 63;
    if (lane == 0) { sh_s[w] = s; sh_ss[w] = ss; }
    __syncthreads();
    if (tid == 0) {
        float S  = sh_s[0]  + sh_s[1]  + sh_s[2]  + sh_s[3];
        float SS = sh_ss[0] + sh_ss[1] + sh_ss[2] + sh_ss[3];
        float mean = S / (float)NN;
        float var  = SS / (float)NN - mean * mean;
        float sc   = g[c] * rsqrtf(var + BN_EPS);
        scale[c] = sc;
        shift[c] = be[c] - mean * sc;
    }
}

// ---------------- in-place BN apply ----------------
__global__ __launch_bounds__(256) void k_bnapply(float* __restrict__ h,
                                                 const float* __restrict__ scale,
                                                 const float* __restrict__ shift) {
    int idx = blockIdx.x * 256 + threadIdx.x;
    if (idx >= NN * 32) return;
    int i  = idx >> 5;
    int c4 = (idx & 31) * 4;
    float4 v  = *(float4*)&h[(size_t)i * 128 + c4];
    float4 sc = *(const float4*)&scale[c4];
    float4 sh = *(const float4*)&shift[c4];
    v.x = fmaf(v.x, sc.x, sh.x); v.y = fmaf(v.y, sc.y, sh.y);
    v.z = fmaf(v.z, sc.z, sh.z); v.w = fmaf(v.w, sc.w, sh.w);
    *(float4*)&h[(size_t)i * 128 + c4] = v;
}

// ---------------- fused MLP head: K=384 GEMM + relu + 128->1 dot + relu ----------------
__global__ __launch_bounds__(256) void gemm_head(const float* __restrict__ X0,
                                                 const float* __restrict__ X1,
                                                 const float* __restrict__ X2,
                                                 const float* __restrict__ Wf1,
                                                 const float* __restrict__ bf1,
                                                 const float* __restrict__ Wf2,
                                                 const float* __restrict__ bf2,
                                                 float* __restrict__ out) {
    __shared__ float xs[16][68];
    __shared__ float ws[16][132];
    __shared__ float red[64];
    int tid  = threadIdx.x;
    int row0 = blockIdx.x * 64;
    int tr = tid & 15;
    int tc = tid >> 4;
    float acc[4][8] = {};
    for (int k0 = 0; k0 < 384; k0 += 16) {
        const float* S = (k0 < 128) ? X0 : (k0 < 256) ? X1 : X2;
        int kb = k0 & 127;
        {
            int r  = tid >> 2;
            int kk = (tid & 3) * 4;
            int gr = row0 + r;
            float4 v = make_float4(0.f, 0.f, 0.f, 0.f);
            if (gr < NN) v = *(const float4*)&S[(size_t)gr * 128 + kb + kk];
            xs[kk + 0][r] = v.x; xs[kk + 1][r] = v.y;
            xs[kk + 2][r] = v.z; xs[kk + 3][r] = v.w;
        }
        {
            int kk = tid >> 4;
            int c  = (tid & 15) * 8;
            *(float4*)&ws[kk][c]     = *(const float4*)&Wf1[(size_t)(k0 + kk) * 128 + c];
            *(float4*)&ws[kk][c + 4] = *(const float4*)&Wf1[(size_t)(k0 + kk) * 128 + c + 4];
        }
        __syncthreads();
        #pragma unroll
        for (int kk = 0; kk < 16; kk++) {
            float a[4], b[8];
            *(float4*)a       = *(const float4*)&xs[kk][tr * 4];
            *(float4*)b       = *(const float4*)&ws[kk][tc * 8];
            *(float4*)(b + 4) = *(const float4*)&ws[kk][tc * 8 + 4];
            #pragma unroll
            for (int i = 0; i < 4; i++)
                #pragma unroll
                for (int j = 0; j < 8; j++)
                    acc[i][j] = fmaf(a[i], b[j], acc[i][j]);
        }
        __syncthreads();
    }
    if (tid < 64) red[tid] = 0.f;
    __syncthreads();
    float w2[8];
    #pragma unroll
    for (int j = 0; j < 8; j++) w2[j] = Wf2[tc * 8 + j];
    #pragma unroll
    for (int i = 0; i < 4; i++) {
        float p = 0.f;
        #pragma unroll
        for (int j = 0; j < 8; j++) {
            float u = fmaxf(acc[i][j] + bf1[tc * 8 + j], 0.f);
            p = fmaf(u, w2[j], p);
        }
        atomicAdd(&red[tr * 4 + i], p);
    }
    __syncthreads();
    if (tid < 64 && row0 + tid < NN)
        out[row0 + tid] = fmaxf(red[tid] + bf2[0], 0.f);
}

// ---------------- launch ----------------
extern "C" void kernel_launch(void* const* d_in, const int* in_sizes, int n_in,
                              void* d_out, int out_size, void* d_ws, size_t ws_size,
                              hipStream_t stream) {
    const float* x   = (const float*)d_in[0];
    const int*   ei  = (const int*)d_in[1];
    const float* ew  = (const float*)d_in[2];
    const float* W1  = (const float*)d_in[3];
    const float* b1  = (const float*)d_in[4];
    const float* W2  = (const float*)d_in[5];
    const float* b2  = (const float*)d_in[6];
    const float* g1  = (const float*)d_in[7];
    const float* be1 = (const float*)d_in[8];
    const float* g2  = (const float*)d_in[9];
    const float* be2 = (const float*)d_in[10];
    const float* Wf1 = (const float*)d_in[11];
    const float* bf1 = (const float*)d_in[12];
    const float* Wf2 = (const float*)d_in[13];
    const float* bf2 = (const float*)d_in[14];
    float* out = (float*)d_out;

    const int* src = ei;
    const int* dst = ei + EE;

    // workspace carve
    float* w = (float*)d_ws;
    float* t       = w;  w += (size_t)NN * 128;
    float* h1      = w;  w += (size_t)NN * 128;
    float* h2      = w;  w += (size_t)NN * 128;
    float* dinv    = w;  w += 50048;
    const int NBLK = (NN + 63) / 64;  // 782
    float* partS   = w;  w += (size_t)NBLK * 128;
    float* partSS  = w;  w += (size_t)NBLK * 128;
    float* scale   = w;  w += 128;
    float* shift   = w;  w += 128;
    float* csr_nrm = w;  w += EE;
    int* iw        = (int*)w;
    int* rowptr    = iw; iw += 50056;
    int* cnt       = iw; iw += 50048;   // cnt and fill adjacent: zeroed together
    int* fill      = iw; iw += 50048;
    int* excl      = iw; iw += 50048;
    int* blksum    = iw; iw += 256;
    int* csr_src   = iw; iw += EE;

    const int GN   = (NN + 255) / 256;       // 196
    const int GE   = (EE + 255) / 256;
    const int GELT = (NN * 32 + 255) / 256;
    const int GAGG = (NN * 64 + 255) / 256;  // 1 wave per node

    // degree / histogram / dinv
    k_deg_init<<<GN, 256, 0, stream>>>(dinv);
    k_zero_int<<<(2 * 50048 + 255) / 256, 256, 0, stream>>>(cnt, 2 * 50048);
    k_deg_hist<<<GE, 256, 0, stream>>>(dst, ew, dinv, cnt);
    k_dinv<<<GN, 256, 0, stream>>>(dinv);

    // CSR build
    k_scan1<<<GN, 256, 0, stream>>>(cnt, excl, blksum);
    k_scan2<<<1, 256, 0, stream>>>(blksum, GN);
    k_scan3<<<GN, 256, 0, stream>>>(excl, blksum, rowptr);
    k_place<<<GE, 256, 0, stream>>>(src, dst, ew, dinv, rowptr, fill, csr_src, csr_nrm);

    // layer 1
    gemm128<<<NBLK, 256, 0, stream>>>(x, W1, t, NN, 128);
    k_aggregate<<<GAGG, 256, 0, stream>>>(t, dinv, b1, rowptr, csr_src, csr_nrm, h1);
    k_colsum<<<NBLK, 256, 0, stream>>>(h1, partS, partSS);
    k_stats<<<128, 256, 0, stream>>>(partS, partSS, NBLK, g1, be1, scale, shift);
    k_bnapply<<<GELT, 256, 0, stream>>>(h1, scale, shift);

    // layer 2
    gemm128<<<NBLK, 256, 0, stream>>>(h1, W2, t, NN, 128);
    k_aggregate<<<GAGG, 256, 0, stream>>>(t, dinv, b2, rowptr, csr_src, csr_nrm, h2);
    k_colsum<<<NBLK, 256, 0, stream>>>(h2, partS, partSS);
    k_stats<<<128, 256, 0, stream>>>(partS, partSS, NBLK, g2, be2, scale, shift);
    k_bnapply<<<GELT, 256, 0, stream>>>(h2, scale, shift);

    // head
    gemm_head<<<NBLK, 256, 0, stream>>>(x, h1, h2, Wf1, bf1, Wf2, bf2, out);
}

// Round 4
// 374.218 us; speedup vs baseline: 9.0328x; 1.2061x over previous
//
#include <hip/hip_runtime.h>
#include <hip/hip_bf16.h>

#define NN 50000
#define EE 800000
constexpr float BN_EPS = 1e-5f;

typedef float  f32x4  __attribute__((ext_vector_type(4)));
typedef short  s16x8  __attribute__((ext_vector_type(8)));
typedef __bf16 bf16x8 __attribute__((ext_vector_type(8)));

// fp32 -> bf16 hi/lo split (RNE both times); hi+lo carries ~16 mantissa bits
__device__ inline void split2(float f, short& h, short& l) {
    unsigned u  = __builtin_bit_cast(unsigned, f);
    unsigned hr = (u + 0x7fffu + ((u >> 16) & 1u)) >> 16;
    h = (short)hr;
    float hf = __builtin_bit_cast(float, hr << 16);
    float r  = f - hf;
    unsigned u2 = __builtin_bit_cast(unsigned, r);
    unsigned lr = (u2 + 0x7fffu + ((u2 >> 16) & 1u)) >> 16;
    l = (short)lr;
}
__device__ inline f32x4 mfma_bf16(s16x8 a, s16x8 b, f32x4 c) {
    return __builtin_amdgcn_mfma_f32_16x16x32_bf16(
        __builtin_bit_cast(bf16x8, a), __builtin_bit_cast(bf16x8, b), c, 0, 0, 0);
}

// ---------------- small utility kernels ----------------
__global__ __launch_bounds__(256) void k_zero_int(int* p, int n) {
    int i = blockIdx.x * 256 + threadIdx.x;
    if (i < n) p[i] = 0;
}
__global__ __launch_bounds__(256) void k_deg_init(float* deg) {
    int i = blockIdx.x * 256 + threadIdx.x;
    if (i < NN) deg[i] = 1.0f;
}
__global__ __launch_bounds__(256) void k_deg_hist(const int* __restrict__ dst,
                                                  const float* __restrict__ w,
                                                  float* deg, int* cnt) {
    int e = blockIdx.x * 256 + threadIdx.x;
    if (e < EE) {
        int d = dst[e];
        unsafeAtomicAdd(&deg[d], w[e]);
        atomicAdd(&cnt[d], 1);
    }
}
__global__ __launch_bounds__(256) void k_dinv(float* deg) {
    int i = blockIdx.x * 256 + threadIdx.x;
    if (i < NN) deg[i] = rsqrtf(deg[i]);
}

// ---------------- CSR build: scan -> place ----------------
__global__ __launch_bounds__(256) void k_scan1(const int* __restrict__ cnt,
                                               int* __restrict__ excl,
                                               int* __restrict__ blksum) {
    __shared__ int sh[256];
    int tid = threadIdx.x;
    int i = blockIdx.x * 256 + tid;
    int v = (i < NN) ? cnt[i] : 0;
    sh[tid] = v;
    __syncthreads();
    #pragma unroll
    for (int off = 1; off < 256; off <<= 1) {
        int x = (tid >= off) ? sh[tid - off] : 0;
        __syncthreads();
        sh[tid] += x;
        __syncthreads();
    }
    if (i < NN) excl[i] = sh[tid] - v;
    if (tid == 255) blksum[blockIdx.x] = sh[255];
}
__global__ __launch_bounds__(256) void k_scan2(int* blksum, int nblk) {
    __shared__ int sh[256];
    int tid = threadIdx.x;
    sh[tid] = (tid < nblk) ? blksum[tid] : 0;
    __syncthreads();
    #pragma unroll
    for (int off = 1; off < 256; off <<= 1) {
        int x = (tid >= off) ? sh[tid - off] : 0;
        __syncthreads();
        sh[tid] += x;
        __syncthreads();
    }
    if (tid < nblk) blksum[tid] = sh[tid];
}
__global__ __launch_bounds__(256) void k_scan3(const int* __restrict__ excl,
                                               const int* __restrict__ blksum,
                                               int* __restrict__ rowptr) {
    int i = blockIdx.x * 256 + threadIdx.x;
    if (i < NN)
        rowptr[i] = excl[i] + (blockIdx.x > 0 ? blksum[blockIdx.x - 1] : 0);
    if (i == 0) rowptr[NN] = EE;
}
__global__ __launch_bounds__(256) void k_place(const int* __restrict__ src,
                                               const int* __restrict__ dst,
                                               const float* __restrict__ w,
                                               const float* __restrict__ dinv,
                                               const int* __restrict__ rowptr,
                                               int* __restrict__ fill,
                                               int* __restrict__ csr_src,
                                               float* __restrict__ csr_nrm) {
    int e = blockIdx.x * 256 + threadIdx.x;
    if (e >= EE) return;
    int s = src[e];
    int d = dst[e];
    int slot = rowptr[d] + atomicAdd(&fill[d], 1);
    csr_src[slot] = s;
    csr_nrm[slot] = dinv[s] * w[e] * dinv[d];
}

// ---------------- weight transpose + bf16 hi/lo split: W[K][128] -> WT[128][K] ----------------
__global__ __launch_bounds__(256) void k_cvt_wT(const float* __restrict__ W,
                                                short* __restrict__ Th,
                                                short* __restrict__ Tl, int K) {
    int idx = blockIdx.x * 256 + threadIdx.x;
    if (idx >= K * 128) return;
    int k = idx >> 7, c = idx & 127;
    short h, l;
    split2(W[idx], h, l);
    Th[c * K + k] = h;
    Tl[c * K + k] = l;
}

// ---------------- MFMA split-bf16 GEMM: Y[n x 128] = X[n x 128] @ W (WT pre-split) ----------------
__global__ __launch_bounds__(256) void gemm_mfma(const float* __restrict__ X,
                                                 const short* __restrict__ WTh,
                                                 const short* __restrict__ WTl,
                                                 float* __restrict__ Y, int n) {
    __shared__ __align__(16) short As[2][64][40];    // [hi/lo][row][k], stride 40 (2-way free)
    __shared__ __align__(16) short Bs[2][128][40];   // [hi/lo][col][k]
    int tid  = threadIdx.x;
    int row0 = blockIdx.x * 64;
    int w = tid >> 6, lane = tid & 63;
    int wr = w >> 1, wc = w & 1;
    int fr = lane & 15, fq = lane >> 4;
    f32x4 acc[2][4] = {};
    for (int k0 = 0; k0 < 128; k0 += 32) {
        {   // stage A (fp32 -> hi/lo in regs -> LDS)
            int r = tid >> 2, seg = tid & 3;
            int gr = row0 + r;
            float f[8];
            if (gr < n) {
                float4 v0 = *(const float4*)&X[(size_t)gr * 128 + k0 + seg * 8];
                float4 v1 = *(const float4*)&X[(size_t)gr * 128 + k0 + seg * 8 + 4];
                f[0]=v0.x; f[1]=v0.y; f[2]=v0.z; f[3]=v0.w;
                f[4]=v1.x; f[5]=v1.y; f[6]=v1.z; f[7]=v1.w;
            } else {
                #pragma unroll
                for (int i = 0; i < 8; i++) f[i] = 0.f;
            }
            short h[8], l[8];
            #pragma unroll
            for (int i = 0; i < 8; i++) split2(f[i], h[i], l[i]);
            *(s16x8*)&As[0][r][seg * 8] = *(s16x8*)h;
            *(s16x8*)&As[1][r][seg * 8] = *(s16x8*)l;
        }
        #pragma unroll
        for (int rd = 0; rd < 2; rd++) {   // stage B (pre-split, 128 cols x 32 k)
            int idx = rd * 256 + tid;
            int c = idx >> 2, seg = idx & 3;
            *(s16x8*)&Bs[0][c][seg * 8] = *(const s16x8*)&WTh[c * 128 + k0 + seg * 8];
            *(s16x8*)&Bs[1][c][seg * 8] = *(const s16x8*)&WTl[c * 128 + k0 + seg * 8];
        }
        __syncthreads();
        s16x8 ah[2], al[2], bh[4], bl[4];
        #pragma unroll
        for (int m = 0; m < 2; m++) {
            int r = wr * 32 + m * 16 + fr;
            ah[m] = *(s16x8*)&As[0][r][fq * 8];
            al[m] = *(s16x8*)&As[1][r][fq * 8];
        }
        #pragma unroll
        for (int nf = 0; nf < 4; nf++) {
            int c = wc * 64 + nf * 16 + fr;
            bh[nf] = *(s16x8*)&Bs[0][c][fq * 8];
            bl[nf] = *(s16x8*)&Bs[1][c][fq * 8];
        }
        #pragma unroll
        for (int m = 0; m < 2; m++)
            #pragma unroll
            for (int nf = 0; nf < 4; nf++) {
                acc[m][nf] = mfma_bf16(ah[m], bh[nf], acc[m][nf]);
                acc[m][nf] = mfma_bf16(ah[m], bl[nf], acc[m][nf]);
                acc[m][nf] = mfma_bf16(al[m], bh[nf], acc[m][nf]);
            }
        __syncthreads();
    }
    #pragma unroll
    for (int m = 0; m < 2; m++)
        #pragma unroll
        for (int nf = 0; nf < 4; nf++)
            #pragma unroll
            for (int j = 0; j < 4; j++) {
                int gr = row0 + wr * 32 + m * 16 + fq * 4 + j;
                int gc = wc * 64 + nf * 16 + fr;
                if (gr < n) Y[(size_t)gr * 128 + gc] = acc[m][nf][j];
            }
}

// ---------------- MFMA head: [x|h1|h2] @ Wf1 + relu + 128->1 dot + relu ----------------
__global__ __launch_bounds__(256) void gemm_head_mfma(const float* __restrict__ X0,
                                                      const float* __restrict__ X1,
                                                      const float* __restrict__ X2,
                                                      const short* __restrict__ WTh,
                                                      const short* __restrict__ WTl,
                                                      const float* __restrict__ bf1,
                                                      const float* __restrict__ Wf2,
                                                      const float* __restrict__ bf2,
                                                      float* __restrict__ out) {
    __shared__ __align__(16) short As[2][64][40];
    __shared__ __align__(16) short Bs[2][128][40];
    __shared__ float red[64];
    int tid  = threadIdx.x;
    int row0 = blockIdx.x * 64;
    int w = tid >> 6, lane = tid & 63;
    int wr = w >> 1, wc = w & 1;
    int fr = lane & 15, fq = lane >> 4;
    f32x4 acc[2][4] = {};
    for (int k0 = 0; k0 < 384; k0 += 32) {
        const float* S = (k0 < 128) ? X0 : (k0 < 256) ? X1 : X2;
        int kb = k0 & 127;
        {
            int r = tid >> 2, seg = tid & 3;
            int gr = row0 + r;
            float f[8];
            if (gr < NN) {
                float4 v0 = *(const float4*)&S[(size_t)gr * 128 + kb + seg * 8];
                float4 v1 = *(const float4*)&S[(size_t)gr * 128 + kb + seg * 8 + 4];
                f[0]=v0.x; f[1]=v0.y; f[2]=v0.z; f[3]=v0.w;
                f[4]=v1.x; f[5]=v1.y; f[6]=v1.z; f[7]=v1.w;
            } else {
                #pragma unroll
                for (int i = 0; i < 8; i++) f[i] = 0.f;
            }
            short h[8], l[8];
            #pragma unroll
            for (int i = 0; i < 8; i++) split2(f[i], h[i], l[i]);
            *(s16x8*)&As[0][r][seg * 8] = *(s16x8*)h;
            *(s16x8*)&As[1][r][seg * 8] = *(s16x8*)l;
        }
        #pragma unroll
        for (int rd = 0; rd < 2; rd++) {
            int idx = rd * 256 + tid;
            int c = idx >> 2, seg = idx & 3;
            *(s16x8*)&Bs[0][c][seg * 8] = *(const s16x8*)&WTh[c * 384 + k0 + seg * 8];
            *(s16x8*)&Bs[1][c][seg * 8] = *(const s16x8*)&WTl[c * 384 + k0 + seg * 8];
        }
        __syncthreads();
        s16x8 ah[2], al[2], bh[4], bl[4];
        #pragma unroll
        for (int m = 0; m < 2; m++) {
            int r = wr * 32 + m * 16 + fr;
            ah[m] = *(s16x8*)&As[0][r][fq * 8];
            al[m] = *(s16x8*)&As[1][r][fq * 8];
        }
        #pragma unroll
        for (int nf = 0; nf < 4; nf++) {
            int c = wc * 64 + nf * 16 + fr;
            bh[nf] = *(s16x8*)&Bs[0][c][fq * 8];
            bl[nf] = *(s16x8*)&Bs[1][c][fq * 8];
        }
        #pragma unroll
        for (int m = 0; m < 2; m++)
            #pragma unroll
            for (int nf = 0; nf < 4; nf++) {
                acc[m][nf] = mfma_bf16(ah[m], bh[nf], acc[m][nf]);
                acc[m][nf] = mfma_bf16(ah[m], bl[nf], acc[m][nf]);
                acc[m][nf] = mfma_bf16(al[m], bh[nf], acc[m][nf]);
            }
        __syncthreads();
    }
    // epilogue: u = relu(acc + bf1), p = sum_cols u * Wf2; rows reduce across fr lanes
    if (tid < 64) red[tid] = 0.f;
    __syncthreads();
    float ps[2][4] = {};
    #pragma unroll
    for (int m = 0; m < 2; m++)
        #pragma unroll
        for (int nf = 0; nf < 4; nf++) {
            int gc = wc * 64 + nf * 16 + fr;
            float b1v = bf1[gc];
            float w2v = Wf2[gc];
            #pragma unroll
            for (int j = 0; j < 4; j++) {
                float u = fmaxf(acc[m][nf][j] + b1v, 0.f);
                ps[m][j] = fmaf(u, w2v, ps[m][j]);
            }
        }
    #pragma unroll
    for (int off = 1; off <= 8; off <<= 1)
        #pragma unroll
        for (int m = 0; m < 2; m++)
            #pragma unroll
            for (int j = 0; j < 4; j++)
                ps[m][j] += __shfl_xor(ps[m][j], off, 64);
    if (fr == 0) {
        #pragma unroll
        for (int m = 0; m < 2; m++)
            #pragma unroll
            for (int j = 0; j < 4; j++)
                atomicAdd(&red[wr * 32 + m * 16 + fq * 4 + j], ps[m][j]);
    }
    __syncthreads();
    if (tid < 64 && row0 + tid < NN)
        out[row0 + tid] = fmaxf(red[tid] + bf2[0], 0.f);
}

// ---------------- aggregate (pull) + ReLU: one wave per dst node ----------------
__global__ __launch_bounds__(256) void k_aggregate(const float* __restrict__ t,
                                                   const float* __restrict__ dinv,
                                                   const float* __restrict__ b,
                                                   const int* __restrict__ rowptr,
                                                   const int* __restrict__ csr_src,
                                                   const float* __restrict__ csr_nrm,
                                                   float* __restrict__ out) {
    int wid  = (blockIdx.x * 256 + threadIdx.x) >> 6;
    int lane = threadIdx.x & 63;
    if (wid >= NN) return;
    float di = dinv[wid];
    float s2 = di * di;
    float2 acc = *(const float2*)&t[(size_t)wid * 128 + lane * 2];
    float2 bb  = *(const float2*)&b[lane * 2];
    acc.x = fmaf(acc.x, s2, bb.x);
    acc.y = fmaf(acc.y, s2, bb.y);
    int e  = rowptr[wid];
    int e1 = rowptr[wid + 1];
    for (; e + 1 < e1; e += 2) {
        int   s0 = csr_src[e],     s1 = csr_src[e + 1];
        float n0 = csr_nrm[e],     n1 = csr_nrm[e + 1];
        float2 v0 = *(const float2*)&t[(size_t)s0 * 128 + lane * 2];
        float2 v1 = *(const float2*)&t[(size_t)s1 * 128 + lane * 2];
        acc.x = fmaf(v0.x, n0, acc.x); acc.y = fmaf(v0.y, n0, acc.y);
        acc.x = fmaf(v1.x, n1, acc.x); acc.y = fmaf(v1.y, n1, acc.y);
    }
    if (e < e1) {
        int   s0 = csr_src[e];
        float n0 = csr_nrm[e];
        float2 v0 = *(const float2*)&t[(size_t)s0 * 128 + lane * 2];
        acc.x = fmaf(v0.x, n0, acc.x); acc.y = fmaf(v0.y, n0, acc.y);
    }
    acc.x = fmaxf(acc.x, 0.f);
    acc.y = fmaxf(acc.y, 0.f);
    *(float2*)&out[(size_t)wid * 128 + lane * 2] = acc;
}

// ---------------- per-block column partial sums ----------------
__global__ __launch_bounds__(256) void k_colsum(const float* __restrict__ h,
                                                float* __restrict__ partS,
                                                float* __restrict__ partSS) {
    int row0 = blockIdx.x * 64;
    int c    = threadIdx.x & 127;
    int half = threadIdx.x >> 7;
    float s = 0.f, ss = 0.f;
    for (int k = 0; k < 32; k++) {
        int r = row0 + half * 32 + k;
        if (r < NN) {
            float v = h[(size_t)r * 128 + c];
            s += v; ss += v * v;
        }
    }
    __shared__ float ls[128], lss[128];
    if (half == 0) { ls[c] = s; lss[c] = ss; }
    __syncthreads();
    if (half == 1) { ls[c] += s; lss[c] += ss; }
    __syncthreads();
    if (half == 0) {
        partS [blockIdx.x * 128 + c] = ls[c];
        partSS[blockIdx.x * 128 + c] = lss[c];
    }
}

// ---------------- parallel reduce partials -> BN scale/shift ----------------
__global__ __launch_bounds__(256) void k_stats(const float* __restrict__ partS,
                                               const float* __restrict__ partSS,
                                               int nblk,
                                               const float* __restrict__ g,
                                               const float* __restrict__ be,
                                               float* __restrict__ scale,
                                               float* __restrict__ shift) {
    int c   = blockIdx.x;
    int tid = threadIdx.x;
    float s = 0.f, ss = 0.f;
    for (int b = tid; b < nblk; b += 256) {
        s  += partS [b * 128 + c];
        ss += partSS[b * 128 + c];
    }
    #pragma unroll
    for (int off = 32; off > 0; off >>= 1) {
        s  += __shfl_down(s,  off, 64);
        ss += __shfl_down(ss, off, 64);
    }
    __shared__ float sh_s[4], sh_ss[4];
    int wv = tid >> 6, lane = tid & 63;
    if (lane == 0) { sh_s[wv] = s; sh_ss[wv] = ss; }
    __syncthreads();
    if (tid == 0) {
        float S  = sh_s[0]  + sh_s[1]  + sh_s[2]  + sh_s[3];
        float SS = sh_ss[0] + sh_ss[1] + sh_ss[2] + sh_ss[3];
        float mean = S / (float)NN;
        float var  = SS / (float)NN - mean * mean;
        float sc   = g[c] * rsqrtf(var + BN_EPS);
        scale[c] = sc;
        shift[c] = be[c] - mean * sc;
    }
}

// ---------------- in-place BN apply ----------------
__global__ __launch_bounds__(256) void k_bnapply(float* __restrict__ h,
                                                 const float* __restrict__ scale,
                                                 const float* __restrict__ shift) {
    int idx = blockIdx.x * 256 + threadIdx.x;
    if (idx >= NN * 32) return;
    int i  = idx >> 5;
    int c4 = (idx & 31) * 4;
    float4 v  = *(float4*)&h[(size_t)i * 128 + c4];
    float4 sc = *(const float4*)&scale[c4];
    float4 sh = *(const float4*)&shift[c4];
    v.x = fmaf(v.x, sc.x, sh.x); v.y = fmaf(v.y, sc.y, sh.y);
    v.z = fmaf(v.z, sc.z, sh.z); v.w = fmaf(v.w, sc.w, sh.w);
    *(float4*)&h[(size_t)i * 128 + c4] = v;
}

// ---------------- launch ----------------
extern "C" void kernel_launch(void* const* d_in, const int* in_sizes, int n_in,
                              void* d_out, int out_size, void* d_ws, size_t ws_size,
                              hipStream_t stream) {
    const float* x   = (const float*)d_in[0];
    const int*   ei  = (const int*)d_in[1];
    const float* ew  = (const float*)d_in[2];
    const float* W1  = (const float*)d_in[3];
    const float* b1  = (const float*)d_in[4];
    const float* W2  = (const float*)d_in[5];
    const float* b2  = (const float*)d_in[6];
    const float* g1  = (const float*)d_in[7];
    const float* be1 = (const float*)d_in[8];
    const float* g2  = (const float*)d_in[9];
    const float* be2 = (const float*)d_in[10];
    const float* Wf1 = (const float*)d_in[11];
    const float* bf1 = (const float*)d_in[12];
    const float* Wf2 = (const float*)d_in[13];
    const float* bf2 = (const float*)d_in[14];
    float* out = (float*)d_out;

    const int* src = ei;
    const int* dst = ei + EE;

    // workspace carve
    float* w = (float*)d_ws;
    float* t       = w;  w += (size_t)NN * 128;
    float* h1      = w;  w += (size_t)NN * 128;
    float* h2      = w;  w += (size_t)NN * 128;
    float* dinv    = w;  w += 50048;
    const int NBLK = (NN + 63) / 64;  // 782
    float* partS   = w;  w += (size_t)NBLK * 128;
    float* partSS  = w;  w += (size_t)NBLK * 128;
    float* scale   = w;  w += 128;
    float* shift   = w;  w += 128;
    float* csr_nrm = w;  w += EE;
    int* iw        = (int*)w;
    int* rowptr    = iw; iw += 50056;
    int* cnt       = iw; iw += 50048;
    int* fill      = iw; iw += 50048;
    int* excl      = iw; iw += 50048;
    int* blksum    = iw; iw += 256;
    int* csr_src   = iw; iw += EE;
    short* sw      = (short*)iw;
    short* W1th    = sw; sw += 128 * 128;
    short* W1tl    = sw; sw += 128 * 128;
    short* W2th    = sw; sw += 128 * 128;
    short* W2tl    = sw; sw += 128 * 128;
    short* Wfth    = sw; sw += 128 * 384;
    short* Wftl    = sw; sw += 128 * 384;

    const int GN   = (NN + 255) / 256;
    const int GE   = (EE + 255) / 256;
    const int GELT = (NN * 32 + 255) / 256;
    const int GAGG = (NN * 64 + 255) / 256;

    // weight transpose + split (cheap, every call)
    k_cvt_wT<<<(128 * 128 + 255) / 256, 256, 0, stream>>>(W1, W1th, W1tl, 128);
    k_cvt_wT<<<(128 * 128 + 255) / 256, 256, 0, stream>>>(W2, W2th, W2tl, 128);
    k_cvt_wT<<<(384 * 128 + 255) / 256, 256, 0, stream>>>(Wf1, Wfth, Wftl, 384);

    // degree / histogram / dinv
    k_deg_init<<<GN, 256, 0, stream>>>(dinv);
    k_zero_int<<<(2 * 50048 + 255) / 256, 256, 0, stream>>>(cnt, 2 * 50048);
    k_deg_hist<<<GE, 256, 0, stream>>>(dst, ew, dinv, cnt);
    k_dinv<<<GN, 256, 0, stream>>>(dinv);

    // CSR build
    k_scan1<<<GN, 256, 0, stream>>>(cnt, excl, blksum);
    k_scan2<<<1, 256, 0, stream>>>(blksum, GN);
    k_scan3<<<GN, 256, 0, stream>>>(excl, blksum, rowptr);
    k_place<<<GE, 256, 0, stream>>>(src, dst, ew, dinv, rowptr, fill, csr_src, csr_nrm);

    // layer 1
    gemm_mfma<<<NBLK, 256, 0, stream>>>(x, W1th, W1tl, t, NN);
    k_aggregate<<<GAGG, 256, 0, stream>>>(t, dinv, b1, rowptr, csr_src, csr_nrm, h1);
    k_colsum<<<NBLK, 256, 0, stream>>>(h1, partS, partSS);
    k_stats<<<128, 256, 0, stream>>>(partS, partSS, NBLK, g1, be1, scale, shift);
    k_bnapply<<<GELT, 256, 0, stream>>>(h1, scale, shift);

    // layer 2
    gemm_mfma<<<NBLK, 256, 0, stream>>>(h1, W2th, W2tl, t, NN);
    k_aggregate<<<GAGG, 256, 0, stream>>>(t, dinv, b2, rowptr, csr_src, csr_nrm, h2);
    k_colsum<<<NBLK, 256, 0, stream>>>(h2, partS, partSS);
    k_stats<<<128, 256, 0, stream>>>(partS, partSS, NBLK, g2, be2, scale, shift);
    k_bnapply<<<GELT, 256, 0, stream>>>(h2, scale, shift);

    // head
    gemm_head_mfma<<<NBLK, 256, 0, stream>>>(x, h1, h2, Wfth, Wftl, bf1, Wf2, bf2, out);
}

// Round 5
// 323.662 us; speedup vs baseline: 10.4437x; 1.1562x over previous
//
#include <hip/hip_runtime.h>
#include <hip/hip_bf16.h>

#define NN 50000
#define EE 800000
constexpr float BN_EPS = 1e-5f;

typedef float  f32x4  __attribute__((ext_vector_type(4)));
typedef short  s16x8  __attribute__((ext_vector_type(8)));
typedef __bf16 bf16x8 __attribute__((ext_vector_type(8)));

// fp32 -> bf16 hi/lo split (RNE both times); hi+lo carries ~16 mantissa bits
__device__ inline void split2(float f, short& h, short& l) {
    unsigned u  = __builtin_bit_cast(unsigned, f);
    unsigned hr = (u + 0x7fffu + ((u >> 16) & 1u)) >> 16;
    h = (short)hr;
    float hf = __builtin_bit_cast(float, hr << 16);
    float r  = f - hf;
    unsigned u2 = __builtin_bit_cast(unsigned, r);
    unsigned lr = (u2 + 0x7fffu + ((u2 >> 16) & 1u)) >> 16;
    l = (short)lr;
}
__device__ inline f32x4 mfma_bf16(s16x8 a, s16x8 b, f32x4 c) {
    return __builtin_amdgcn_mfma_f32_16x16x32_bf16(
        __builtin_bit_cast(bf16x8, a), __builtin_bit_cast(bf16x8, b), c, 0, 0, 0);
}

// ---------------- small utility kernels ----------------
__global__ __launch_bounds__(256) void k_zero_int(int* p, int n) {
    int i = blockIdx.x * 256 + threadIdx.x;
    if (i < n) p[i] = 0;
}

// ---------------- CSR build: 1 atomic/edge total ----------------
// pass 1: histogram + per-edge within-row rank (arrival order)
__global__ __launch_bounds__(256) void k_hist_rank(const int* __restrict__ dst,
                                                   int* __restrict__ cnt,
                                                   int* __restrict__ rank) {
    int e = blockIdx.x * 256 + threadIdx.x;
    if (e < EE) rank[e] = atomicAdd(&cnt[dst[e]], 1);
}
__global__ __launch_bounds__(256) void k_scan1(const int* __restrict__ cnt,
                                               int* __restrict__ excl,
                                               int* __restrict__ blksum) {
    __shared__ int sh[256];
    int tid = threadIdx.x;
    int i = blockIdx.x * 256 + tid;
    int v = (i < NN) ? cnt[i] : 0;
    sh[tid] = v;
    __syncthreads();
    #pragma unroll
    for (int off = 1; off < 256; off <<= 1) {
        int x = (tid >= off) ? sh[tid - off] : 0;
        __syncthreads();
        sh[tid] += x;
        __syncthreads();
    }
    if (i < NN) excl[i] = sh[tid] - v;
    if (tid == 255) blksum[blockIdx.x] = sh[255];
}
__global__ __launch_bounds__(256) void k_scan2(int* blksum, int nblk) {
    __shared__ int sh[256];
    int tid = threadIdx.x;
    sh[tid] = (tid < nblk) ? blksum[tid] : 0;
    __syncthreads();
    #pragma unroll
    for (int off = 1; off < 256; off <<= 1) {
        int x = (tid >= off) ? sh[tid - off] : 0;
        __syncthreads();
        sh[tid] += x;
        __syncthreads();
    }
    if (tid < nblk) blksum[tid] = sh[tid];
}
__global__ __launch_bounds__(256) void k_scan3(const int* __restrict__ excl,
                                               const int* __restrict__ blksum,
                                               int* __restrict__ rowptr) {
    int i = blockIdx.x * 256 + threadIdx.x;
    if (i < NN)
        rowptr[i] = excl[i] + (blockIdx.x > 0 ? blksum[blockIdx.x - 1] : 0);
    if (i == 0) rowptr[NN] = EE;
}
// pass 2: place edges (no atomics)
__global__ __launch_bounds__(256) void k_place2(const int* __restrict__ src,
                                                const int* __restrict__ dst,
                                                const float* __restrict__ w,
                                                const int* __restrict__ rowptr,
                                                const int* __restrict__ rank,
                                                int* __restrict__ csr_src,
                                                float* __restrict__ csr_w) {
    int e = blockIdx.x * 256 + threadIdx.x;
    if (e >= EE) return;
    int slot = rowptr[dst[e]] + rank[e];
    csr_src[slot] = src[e];
    csr_w[slot]   = w[e];
}
// degree from CSR (no atomics) -> dinv
__global__ __launch_bounds__(256) void k_deg_dinv(const int* __restrict__ rowptr,
                                                  const float* __restrict__ csr_w,
                                                  float* __restrict__ dinv) {
    int i = blockIdx.x * 256 + threadIdx.x;
    if (i >= NN) return;
    int e0 = rowptr[i], e1 = rowptr[i + 1];
    float s = 1.0f;
    for (int e = e0; e < e1; e++) s += csr_w[e];
    dinv[i] = rsqrtf(s);
}

// ---------------- weight transpose + bf16 hi/lo split: W[K][128] -> WT[128][K] ----------------
__global__ __launch_bounds__(256) void k_cvt_wT(const float* __restrict__ W,
                                                short* __restrict__ Th,
                                                short* __restrict__ Tl, int K) {
    int idx = blockIdx.x * 256 + threadIdx.x;
    if (idx >= K * 128) return;
    int k = idx >> 7, c = idx & 127;
    short h, l;
    split2(W[idx], h, l);
    Th[c * K + k] = h;
    Tl[c * K + k] = l;
}

// ---------------- MFMA split-bf16 GEMM: Y[n x 128] = X[n x 128] @ W ----------------
__global__ __launch_bounds__(256) void gemm_mfma(const float* __restrict__ X,
                                                 const short* __restrict__ WTh,
                                                 const short* __restrict__ WTl,
                                                 float* __restrict__ Y, int n) {
    __shared__ __align__(16) short As[2][64][40];
    __shared__ __align__(16) short Bs[2][128][40];
    int tid  = threadIdx.x;
    int row0 = blockIdx.x * 64;
    int w = tid >> 6, lane = tid & 63;
    int wr = w >> 1, wc = w & 1;
    int fr = lane & 15, fq = lane >> 4;
    f32x4 acc[2][4] = {};
    for (int k0 = 0; k0 < 128; k0 += 32) {
        {
            int r = tid >> 2, seg = tid & 3;
            int gr = row0 + r;
            float f[8];
            if (gr < n) {
                float4 v0 = *(const float4*)&X[(size_t)gr * 128 + k0 + seg * 8];
                float4 v1 = *(const float4*)&X[(size_t)gr * 128 + k0 + seg * 8 + 4];
                f[0]=v0.x; f[1]=v0.y; f[2]=v0.z; f[3]=v0.w;
                f[4]=v1.x; f[5]=v1.y; f[6]=v1.z; f[7]=v1.w;
            } else {
                #pragma unroll
                for (int i = 0; i < 8; i++) f[i] = 0.f;
            }
            short h[8], l[8];
            #pragma unroll
            for (int i = 0; i < 8; i++) split2(f[i], h[i], l[i]);
            *(s16x8*)&As[0][r][seg * 8] = *(s16x8*)h;
            *(s16x8*)&As[1][r][seg * 8] = *(s16x8*)l;
        }
        #pragma unroll
        for (int rd = 0; rd < 2; rd++) {
            int idx = rd * 256 + tid;
            int c = idx >> 2, seg = idx & 3;
            *(s16x8*)&Bs[0][c][seg * 8] = *(const s16x8*)&WTh[c * 128 + k0 + seg * 8];
            *(s16x8*)&Bs[1][c][seg * 8] = *(const s16x8*)&WTl[c * 128 + k0 + seg * 8];
        }
        __syncthreads();
        s16x8 ah[2], al[2], bh[4], bl[4];
        #pragma unroll
        for (int m = 0; m < 2; m++) {
            int r = wr * 32 + m * 16 + fr;
            ah[m] = *(s16x8*)&As[0][r][fq * 8];
            al[m] = *(s16x8*)&As[1][r][fq * 8];
        }
        #pragma unroll
        for (int nf = 0; nf < 4; nf++) {
            int c = wc * 64 + nf * 16 + fr;
            bh[nf] = *(s16x8*)&Bs[0][c][fq * 8];
            bl[nf] = *(s16x8*)&Bs[1][c][fq * 8];
        }
        #pragma unroll
        for (int m = 0; m < 2; m++)
            #pragma unroll
            for (int nf = 0; nf < 4; nf++) {
                acc[m][nf] = mfma_bf16(ah[m], bh[nf], acc[m][nf]);
                acc[m][nf] = mfma_bf16(ah[m], bl[nf], acc[m][nf]);
                acc[m][nf] = mfma_bf16(al[m], bh[nf], acc[m][nf]);
            }
        __syncthreads();
    }
    #pragma unroll
    for (int m = 0; m < 2; m++)
        #pragma unroll
        for (int nf = 0; nf < 4; nf++)
            #pragma unroll
            for (int j = 0; j < 4; j++) {
                int gr = row0 + wr * 32 + m * 16 + fq * 4 + j;
                int gc = wc * 64 + nf * 16 + fr;
                if (gr < n) Y[(size_t)gr * 128 + gc] = acc[m][nf][j];
            }
}

// ---------------- MFMA head: [x|h1|h2] @ Wf1 + relu + 128->1 dot + relu ----------------
__global__ __launch_bounds__(256) void gemm_head_mfma(const float* __restrict__ X0,
                                                      const float* __restrict__ X1,
                                                      const float* __restrict__ X2,
                                                      const short* __restrict__ WTh,
                                                      const short* __restrict__ WTl,
                                                      const float* __restrict__ bf1,
                                                      const float* __restrict__ Wf2,
                                                      const float* __restrict__ bf2,
                                                      float* __restrict__ out) {
    __shared__ __align__(16) short As[2][64][40];
    __shared__ __align__(16) short Bs[2][128][40];
    __shared__ float red[64];
    int tid  = threadIdx.x;
    int row0 = blockIdx.x * 64;
    int w = tid >> 6, lane = tid & 63;
    int wr = w >> 1, wc = w & 1;
    int fr = lane & 15, fq = lane >> 4;
    f32x4 acc[2][4] = {};
    for (int k0 = 0; k0 < 384; k0 += 32) {
        const float* S = (k0 < 128) ? X0 : (k0 < 256) ? X1 : X2;
        int kb = k0 & 127;
        {
            int r = tid >> 2, seg = tid & 3;
            int gr = row0 + r;
            float f[8];
            if (gr < NN) {
                float4 v0 = *(const float4*)&S[(size_t)gr * 128 + kb + seg * 8];
                float4 v1 = *(const float4*)&S[(size_t)gr * 128 + kb + seg * 8 + 4];
                f[0]=v0.x; f[1]=v0.y; f[2]=v0.z; f[3]=v0.w;
                f[4]=v1.x; f[5]=v1.y; f[6]=v1.z; f[7]=v1.w;
            } else {
                #pragma unroll
                for (int i = 0; i < 8; i++) f[i] = 0.f;
            }
            short h[8], l[8];
            #pragma unroll
            for (int i = 0; i < 8; i++) split2(f[i], h[i], l[i]);
            *(s16x8*)&As[0][r][seg * 8] = *(s16x8*)h;
            *(s16x8*)&As[1][r][seg * 8] = *(s16x8*)l;
        }
        #pragma unroll
        for (int rd = 0; rd < 2; rd++) {
            int idx = rd * 256 + tid;
            int c = idx >> 2, seg = idx & 3;
            *(s16x8*)&Bs[0][c][seg * 8] = *(const s16x8*)&WTh[c * 384 + k0 + seg * 8];
            *(s16x8*)&Bs[1][c][seg * 8] = *(const s16x8*)&WTl[c * 384 + k0 + seg * 8];
        }
        __syncthreads();
        s16x8 ah[2], al[2], bh[4], bl[4];
        #pragma unroll
        for (int m = 0; m < 2; m++) {
            int r = wr * 32 + m * 16 + fr;
            ah[m] = *(s16x8*)&As[0][r][fq * 8];
            al[m] = *(s16x8*)&As[1][r][fq * 8];
        }
        #pragma unroll
        for (int nf = 0; nf < 4; nf++) {
            int c = wc * 64 + nf * 16 + fr;
            bh[nf] = *(s16x8*)&Bs[0][c][fq * 8];
            bl[nf] = *(s16x8*)&Bs[1][c][fq * 8];
        }
        #pragma unroll
        for (int m = 0; m < 2; m++)
            #pragma unroll
            for (int nf = 0; nf < 4; nf++) {
                acc[m][nf] = mfma_bf16(ah[m], bh[nf], acc[m][nf]);
                acc[m][nf] = mfma_bf16(ah[m], bl[nf], acc[m][nf]);
                acc[m][nf] = mfma_bf16(al[m], bh[nf], acc[m][nf]);
            }
        __syncthreads();
    }
    if (tid < 64) red[tid] = 0.f;
    __syncthreads();
    float ps[2][4] = {};
    #pragma unroll
    for (int m = 0; m < 2; m++)
        #pragma unroll
        for (int nf = 0; nf < 4; nf++) {
            int gc = wc * 64 + nf * 16 + fr;
            float b1v = bf1[gc];
            float w2v = Wf2[gc];
            #pragma unroll
            for (int j = 0; j < 4; j++) {
                float u = fmaxf(acc[m][nf][j] + b1v, 0.f);
                ps[m][j] = fmaf(u, w2v, ps[m][j]);
            }
        }
    #pragma unroll
    for (int off = 1; off <= 8; off <<= 1)
        #pragma unroll
        for (int m = 0; m < 2; m++)
            #pragma unroll
            for (int j = 0; j < 4; j++)
                ps[m][j] += __shfl_xor(ps[m][j], off, 64);
    if (fr == 0) {
        #pragma unroll
        for (int m = 0; m < 2; m++)
            #pragma unroll
            for (int j = 0; j < 4; j++)
                atomicAdd(&red[wr * 32 + m * 16 + fq * 4 + j], ps[m][j]);
    }
    __syncthreads();
    if (tid < 64 && row0 + tid < NN)
        out[row0 + tid] = fmaxf(red[tid] + bf2[0], 0.f);
}

// ---------------- aggregate (pull) + ReLU, norm on the fly ----------------
// out[d] = relu( (t[d]*dinv_d + sum_e dinv[s]*w*t[s]) * dinv_d + b )
__global__ __launch_bounds__(256) void k_aggregate(const float* __restrict__ t,
                                                   const float* __restrict__ dinv,
                                                   const float* __restrict__ b,
                                                   const int* __restrict__ rowptr,
                                                   const int* __restrict__ csr_src,
                                                   const float* __restrict__ csr_w,
                                                   float* __restrict__ out) {
    int wid  = (blockIdx.x * 256 + threadIdx.x) >> 6;
    int lane = threadIdx.x & 63;
    if (wid >= NN) return;
    float di = dinv[wid];
    float2 a0 = *(const float2*)&t[(size_t)wid * 128 + lane * 2];
    float2 acc = make_float2(a0.x * di, a0.y * di);
    int e  = rowptr[wid];
    int e1 = rowptr[wid + 1];
    for (; e + 1 < e1; e += 2) {
        int   s0 = csr_src[e],   s1 = csr_src[e + 1];
        float c0 = dinv[s0] * csr_w[e];
        float c1 = dinv[s1] * csr_w[e + 1];
        float2 v0 = *(const float2*)&t[(size_t)s0 * 128 + lane * 2];
        float2 v1 = *(const float2*)&t[(size_t)s1 * 128 + lane * 2];
        acc.x = fmaf(v0.x, c0, acc.x); acc.y = fmaf(v0.y, c0, acc.y);
        acc.x = fmaf(v1.x, c1, acc.x); acc.y = fmaf(v1.y, c1, acc.y);
    }
    if (e < e1) {
        int   s0 = csr_src[e];
        float c0 = dinv[s0] * csr_w[e];
        float2 v0 = *(const float2*)&t[(size_t)s0 * 128 + lane * 2];
        acc.x = fmaf(v0.x, c0, acc.x); acc.y = fmaf(v0.y, c0, acc.y);
    }
    float2 bb = *(const float2*)&b[lane * 2];
    acc.x = fmaxf(fmaf(acc.x, di, bb.x), 0.f);
    acc.y = fmaxf(fmaf(acc.y, di, bb.y), 0.f);
    *(float2*)&out[(size_t)wid * 128 + lane * 2] = acc;
}

// ---------------- per-block column partial sums ----------------
__global__ __launch_bounds__(256) void k_colsum(const float* __restrict__ h,
                                                float* __restrict__ partS,
                                                float* __restrict__ partSS) {
    int row0 = blockIdx.x * 64;
    int c    = threadIdx.x & 127;
    int half = threadIdx.x >> 7;
    float s = 0.f, ss = 0.f;
    for (int k = 0; k < 32; k++) {
        int r = row0 + half * 32 + k;
        if (r < NN) {
            float v = h[(size_t)r * 128 + c];
            s += v; ss += v * v;
        }
    }
    __shared__ float ls[128], lss[128];
    if (half == 0) { ls[c] = s; lss[c] = ss; }
    __syncthreads();
    if (half == 1) { ls[c] += s; lss[c] += ss; }
    __syncthreads();
    if (half == 0) {
        partS [blockIdx.x * 128 + c] = ls[c];
        partSS[blockIdx.x * 128 + c] = lss[c];
    }
}

// ---------------- parallel reduce partials -> BN scale/shift ----------------
__global__ __launch_bounds__(256) void k_stats(const float* __restrict__ partS,
                                               const float* __restrict__ partSS,
                                               int nblk,
                                               const float* __restrict__ g,
                                               const float* __restrict__ be,
                                               float* __restrict__ scale,
                                               float* __restrict__ shift) {
    int c   = blockIdx.x;
    int tid = threadIdx.x;
    float s = 0.f, ss = 0.f;
    for (int b = tid; b < nblk; b += 256) {
        s  += partS [b * 128 + c];
        ss += partSS[b * 128 + c];
    }
    #pragma unroll
    for (int off = 32; off > 0; off >>= 1) {
        s  += __shfl_down(s,  off, 64);
        ss += __shfl_down(ss, off, 64);
    }
    __shared__ float sh_s[4], sh_ss[4];
    int wv = tid >> 6, lane = tid & 63;
    if (lane == 0) { sh_s[wv] = s; sh_ss[wv] = ss; }
    __syncthreads();
    if (tid == 0) {
        float S  = sh_s[0]  + sh_s[1]  + sh_s[2]  + sh_s[3];
        float SS = sh_ss[0] + sh_ss[1] + sh_ss[2] + sh_ss[3];
        float mean = S / (float)NN;
        float var  = SS / (float)NN - mean * mean;
        float sc   = g[c] * rsqrtf(var + BN_EPS);
        scale[c] = sc;
        shift[c] = be[c] - mean * sc;
    }
}

// ---------------- in-place BN apply ----------------
__global__ __launch_bounds__(256) void k_bnapply(float* __restrict__ h,
                                                 const float* __restrict__ scale,
                                                 const float* __restrict__ shift) {
    int idx = blockIdx.x * 256 + threadIdx.x;
    if (idx >= NN * 32) return;
    int i  = idx >> 5;
    int c4 = (idx & 31) * 4;
    float4 v  = *(float4*)&h[(size_t)i * 128 + c4];
    float4 sc = *(const float4*)&scale[c4];
    float4 sh = *(const float4*)&shift[c4];
    v.x = fmaf(v.x, sc.x, sh.x); v.y = fmaf(v.y, sc.y, sh.y);
    v.z = fmaf(v.z, sc.z, sh.z); v.w = fmaf(v.w, sc.w, sh.w);
    *(float4*)&h[(size_t)i * 128 + c4] = v;
}

// ---------------- launch ----------------
extern "C" void kernel_launch(void* const* d_in, const int* in_sizes, int n_in,
                              void* d_out, int out_size, void* d_ws, size_t ws_size,
                              hipStream_t stream) {
    const float* x   = (const float*)d_in[0];
    const int*   ei  = (const int*)d_in[1];
    const float* ew  = (const float*)d_in[2];
    const float* W1  = (const float*)d_in[3];
    const float* b1  = (const float*)d_in[4];
    const float* W2  = (const float*)d_in[5];
    const float* b2  = (const float*)d_in[6];
    const float* g1  = (const float*)d_in[7];
    const float* be1 = (const float*)d_in[8];
    const float* g2  = (const float*)d_in[9];
    const float* be2 = (const float*)d_in[10];
    const float* Wf1 = (const float*)d_in[11];
    const float* bf1 = (const float*)d_in[12];
    const float* Wf2 = (const float*)d_in[13];
    const float* bf2 = (const float*)d_in[14];
    float* out = (float*)d_out;

    const int* src = ei;
    const int* dst = ei + EE;

    // workspace carve
    float* w = (float*)d_ws;
    float* t       = w;  w += (size_t)NN * 128;
    float* h1      = w;  w += (size_t)NN * 128;
    float* h2      = w;  w += (size_t)NN * 128;
    float* dinv    = w;  w += 50048;
    const int NBLK = (NN + 63) / 64;  // 782
    float* partS   = w;  w += (size_t)NBLK * 128;
    float* partSS  = w;  w += (size_t)NBLK * 128;
    float* scale   = w;  w += 128;
    float* shift   = w;  w += 128;
    float* csr_w   = w;  w += EE;
    int* iw        = (int*)w;
    int* rowptr    = iw; iw += 50056;
    int* cnt       = iw; iw += 50048;
    int* excl      = iw; iw += 50048;
    int* blksum    = iw; iw += 256;
    int* csr_src   = iw; iw += EE;
    // rank aliases t: CSR build completes (same stream) before gemm writes t
    int* rank      = (int*)t;

    const int GN   = (NN + 255) / 256;
    const int GE   = (EE + 255) / 256;
    const int GELT = (NN * 32 + 255) / 256;
    const int GAGG = (NN * 64 + 255) / 256;

    // weight transpose + split
    k_cvt_wT<<<(128 * 128 + 255) / 256, 256, 0, stream>>>(W1, W1 ? ((short*)(iw)) : nullptr, ((short*)(iw)) + 128 * 128, 128);
    short* sw   = (short*)iw;
    short* W1th = sw; sw += 128 * 128;
    short* W1tl = sw; sw += 128 * 128;
    short* W2th = sw; sw += 128 * 128;
    short* W2tl = sw; sw += 128 * 128;
    short* Wfth = sw; sw += 128 * 384;
    short* Wftl = sw; sw += 128 * 384;
    // (first k_cvt_wT above already targeted W1th/W1tl)
    k_cvt_wT<<<(128 * 128 + 255) / 256, 256, 0, stream>>>(W2, W2th, W2tl, 128);
    k_cvt_wT<<<(384 * 128 + 255) / 256, 256, 0, stream>>>(Wf1, Wfth, Wftl, 384);

    // CSR build: zero cnt -> hist+rank (1 atomic/edge) -> scan -> place (no atomics)
    k_zero_int<<<GN, 256, 0, stream>>>(cnt, 50048);
    k_hist_rank<<<GE, 256, 0, stream>>>(dst, cnt, rank);
    k_scan1<<<GN, 256, 0, stream>>>(cnt, excl, blksum);
    k_scan2<<<1, 256, 0, stream>>>(blksum, GN);
    k_scan3<<<GN, 256, 0, stream>>>(excl, blksum, rowptr);
    k_place2<<<GE, 256, 0, stream>>>(src, dst, ew, rowptr, rank, csr_src, csr_w);
    k_deg_dinv<<<GN, 256, 0, stream>>>(rowptr, csr_w, dinv);

    // layer 1
    gemm_mfma<<<NBLK, 256, 0, stream>>>(x, W1th, W1tl, t, NN);
    k_aggregate<<<GAGG, 256, 0, stream>>>(t, dinv, b1, rowptr, csr_src, csr_w, h1);
    k_colsum<<<NBLK, 256, 0, stream>>>(h1, partS, partSS);
    k_stats<<<128, 256, 0, stream>>>(partS, partSS, NBLK, g1, be1, scale, shift);
    k_bnapply<<<GELT, 256, 0, stream>>>(h1, scale, shift);

    // layer 2
    gemm_mfma<<<NBLK, 256, 0, stream>>>(h1, W2th, W2tl, t, NN);
    k_aggregate<<<GAGG, 256, 0, stream>>>(t, dinv, b2, rowptr, csr_src, csr_w, h2);
    k_colsum<<<NBLK, 256, 0, stream>>>(h2, partS, partSS);
    k_stats<<<128, 256, 0, stream>>>(partS, partSS, NBLK, g2, be2, scale, shift);
    k_bnapply<<<GELT, 256, 0, stream>>>(h2, scale, shift);

    // head
    gemm_head_mfma<<<NBLK, 256, 0, stream>>>(x, h1, h2, Wfth, Wftl, bf1, Wf2, bf2, out);
}